// Round 16
// baseline (258.369 us; speedup 1.0000x reference)
//
#include <hip/hip_runtime.h>
#include <cstddef>

#define D_MODEL   512
#define D_INNER   1024
#define D_STATE   16
#define DT_RANK   32
#define SEQ_L     1024
#define BATCH     2
#define NLAYER    2
#define M_ROWS    (BATCH * SEQ_L)   // 2048
#define NC        32                // scan chunks
#define LC        (SEQ_L / NC)      // 32 timesteps per chunk

typedef __bf16 bf16x8 __attribute__((ext_vector_type(8)));
typedef float  f32x4  __attribute__((ext_vector_type(4)));

__device__ __forceinline__ float softplus_f(float x) {
    return fmaxf(x, 0.f) + log1pf(expf(-fabsf(x)));
}
__device__ __forceinline__ float silu_f(float x) {
    return x / (1.f + __expf(-x));
}
__device__ __forceinline__ unsigned short f2bf(float f) {
    unsigned u = __float_as_uint(f);
    return (unsigned short)((u + 0x7fffu + ((u >> 16) & 1u)) >> 16);
}
__device__ __forceinline__ float bf2f(unsigned short v) {
    return __uint_as_float(((unsigned)v) << 16);
}
__device__ __forceinline__ unsigned pack_bf2(float lo, float hi) {
    return (unsigned)f2bf(lo) | ((unsigned)f2bf(hi) << 16);
}

// ==== init: embed gather + layer-0 rmsnorm + both weight cast-transposes ====
// grid (64, 32, 5): z==4 -> embed+rms0 (512 blocks, 4 rows each);
//                   z<2 -> in_w layer z; z in {2,3} -> out_w layer z-2.
__global__ __launch_bounds__(256) void init_kernel(const int* __restrict__ ids,
                                                   const float* __restrict__ emb,
                                                   const float* __restrict__ nw0,
                                                   const float* __restrict__ in_w,
                                                   const float* __restrict__ out_w,
                                                   float* __restrict__ x,
                                                   unsigned short* __restrict__ xn_bf,
                                                   unsigned short* __restrict__ in_wt_all,
                                                   unsigned short* __restrict__ out_wt_all) {
    int z = blockIdx.z;
    if (z == 4) {                                   // embed + layer-0 rmsnorm
        int blk = blockIdx.y * 64 + blockIdx.x;
        if (blk >= 512) return;
        int wave = threadIdx.x >> 6, lane = threadIdx.x & 63;
        int m = blk * 4 + wave;
        int row = ids[m];
        const float* ep = emb + (size_t)row * D_MODEL;
        float4 v0 = *(const float4*)&ep[lane * 4];
        float4 v1 = *(const float4*)&ep[256 + lane * 4];
        float* xp = x + (size_t)m * D_MODEL;
        *(float4*)&xp[lane * 4] = v0;
        *(float4*)&xp[256 + lane * 4] = v1;
        float ss = v0.x*v0.x + v0.y*v0.y + v0.z*v0.z + v0.w*v0.w
                 + v1.x*v1.x + v1.y*v1.y + v1.z*v1.z + v1.w*v1.w;
        #pragma unroll
        for (int off = 32; off > 0; off >>= 1) ss += __shfl_xor(ss, off);
        float scale = rsqrtf(ss * (1.f / D_MODEL) + 1e-5f);
        float4 w0 = *(const float4*)&nw0[lane * 4];
        float4 w1 = *(const float4*)&nw0[256 + lane * 4];
        unsigned short* op = xn_bf + (size_t)m * D_MODEL;
        uint2 p0, p1;
        p0.x = pack_bf2(v0.x * scale * w0.x, v0.y * scale * w0.y);
        p0.y = pack_bf2(v0.z * scale * w0.z, v0.w * scale * w0.w);
        p1.x = pack_bf2(v1.x * scale * w1.x, v1.y * scale * w1.y);
        p1.y = pack_bf2(v1.z * scale * w1.z, v1.w * scale * w1.w);
        *(uint2*)&op[lane * 4] = p0;
        *(uint2*)&op[256 + lane * 4] = p1;
        return;
    }
    const float* W; unsigned short* Wt; int K, N;
    if (z < 2) {
        if (blockIdx.x >= 64 || blockIdx.y >= 16) return;
        W = in_w + (size_t)z * 512 * 2048; Wt = in_wt_all + (size_t)z * 2048 * 512;
        K = 512; N = 2048;
    } else {
        int zz = z - 2;
        if (blockIdx.x >= 16 || blockIdx.y >= 32) return;
        W = out_w + (size_t)zz * 1024 * 512; Wt = out_wt_all + (size_t)zz * 512 * 1024;
        K = 1024; N = 512;
    }
    __shared__ float tile[32][33];
    int n0 = blockIdx.x * 32, k0 = blockIdx.y * 32;
    int tx = threadIdx.x & 31, ty = threadIdx.x >> 5;
    #pragma unroll
    for (int i = 0; i < 4; ++i)
        tile[ty + i*8][tx] = W[(size_t)(k0 + ty + i*8) * N + n0 + tx];
    __syncthreads();
    #pragma unroll
    for (int i = 0; i < 4; ++i)
        Wt[(size_t)(n0 + ty + i*8) * K + k0 + tx] = f2bf(tile[tx][ty + i*8]);
}

// -------- rmsnorm (bf16 out), used for layer >= 1 ---------------------------
__global__ __launch_bounds__(64) void rmsnorm_bf_kernel(const float* __restrict__ x,
                                                        const float* __restrict__ w,
                                                        unsigned short* __restrict__ out) {
    int row = blockIdx.x;
    int tid = threadIdx.x;
    const float* xp = x + (size_t)row * D_MODEL;
    float4 v0 = *(const float4*)&xp[tid * 4];
    float4 v1 = *(const float4*)&xp[256 + tid * 4];
    float ss = v0.x*v0.x + v0.y*v0.y + v0.z*v0.z + v0.w*v0.w
             + v1.x*v1.x + v1.y*v1.y + v1.z*v1.z + v1.w*v1.w;
    #pragma unroll
    for (int off = 32; off > 0; off >>= 1) ss += __shfl_xor(ss, off);
    float scale = rsqrtf(ss * (1.f / D_MODEL) + 1e-5f);
    float4 w0 = *(const float4*)&w[tid * 4];
    float4 w1 = *(const float4*)&w[256 + tid * 4];
    unsigned short* op = out + (size_t)row * D_MODEL;
    uint2 p0, p1;
    p0.x = pack_bf2(v0.x * scale * w0.x, v0.y * scale * w0.y);
    p0.y = pack_bf2(v0.z * scale * w0.z, v0.w * scale * w0.w);
    p1.x = pack_bf2(v1.x * scale * w1.x, v1.y * scale * w1.y);
    p1.y = pack_bf2(v1.z * scale * w1.z, v1.w * scale * w1.w);
    *(uint2*)&op[tid * 4] = p0;
    *(uint2*)&op[256 + tid * 4] = p1;
}

// ===== templated bf16 MFMA GEMM =============================================
// BM x BN tile, BK=64, 4 waves (2x2); EPI 2: C(f32) += acc; EPI 3: Cb = acc.
template<int BMT, int BNT, int EPI>
__global__ __launch_bounds__(256) void gemm_mfma_t(const unsigned short* __restrict__ A,
                                                   const unsigned short* __restrict__ Bt,
                                                   float* __restrict__ C,
                                                   unsigned short* __restrict__ Cb,
                                                   int K, int ldc) {
    constexpr int FM = BMT / 32;
    constexpr int FN = BNT / 32;
    __shared__ unsigned short As[BMT * 64];
    __shared__ unsigned short Bs[BNT * 64];
    int m0 = blockIdx.y * BMT;
    int n0 = blockIdx.x * BNT;
    int t = threadIdx.x;
    int lane = t & 63, wave = t >> 6;
    int wr = wave >> 1, wc = wave & 1;
    int srow = t >> 3;
    int sc8  = t & 7;
    f32x4 acc[FM][FN] = {};

    for (int k0 = 0; k0 < K; k0 += 64) {
        __syncthreads();
        #pragma unroll
        for (int i = 0; i < BMT / 32; ++i) {
            int row = i * 32 + srow;
            int csrc = sc8 ^ (row & 7);
            __builtin_amdgcn_global_load_lds(
                (const __attribute__((address_space(1))) void*)
                    &A[(size_t)(m0 + row) * K + k0 + csrc * 8],
                (__attribute__((address_space(3))) void*)
                    &As[row * 64 + sc8 * 8], 16, 0, 0);
        }
        #pragma unroll
        for (int i = 0; i < BNT / 32; ++i) {
            int row = i * 32 + srow;
            int csrc = sc8 ^ (row & 7);
            __builtin_amdgcn_global_load_lds(
                (const __attribute__((address_space(1))) void*)
                    &Bt[(size_t)(n0 + row) * K + k0 + csrc * 8],
                (__attribute__((address_space(3))) void*)
                    &Bs[row * 64 + sc8 * 8], 16, 0, 0);
        }
        __syncthreads();
        #pragma unroll
        for (int ks = 0; ks < 2; ++ks) {
            bf16x8 av[FM], bv[FN];
            #pragma unroll
            for (int f = 0; f < FM; ++f) {
                int ar = wr * (FM * 16) + f * 16 + (lane & 15);
                int ac = (ks * 4 + (lane >> 4)) ^ (ar & 7);
                av[f] = *reinterpret_cast<const bf16x8*>(&As[ar * 64 + ac * 8]);
            }
            #pragma unroll
            for (int f = 0; f < FN; ++f) {
                int br = wc * (FN * 16) + f * 16 + (lane & 15);
                int bc = (ks * 4 + (lane >> 4)) ^ (br & 7);
                bv[f] = *reinterpret_cast<const bf16x8*>(&Bs[br * 64 + bc * 8]);
            }
            #pragma unroll
            for (int fm = 0; fm < FM; ++fm)
                #pragma unroll
                for (int fn = 0; fn < FN; ++fn)
                    acc[fm][fn] = __builtin_amdgcn_mfma_f32_16x16x32_bf16(
                        av[fm], bv[fn], acc[fm][fn], 0, 0, 0);
        }
    }
    #pragma unroll
    for (int fm = 0; fm < FM; ++fm)
        #pragma unroll
        for (int fn = 0; fn < FN; ++fn) {
            int row = m0 + wr * (FM * 16) + fm * 16 + (lane >> 4) * 4;
            int col = n0 + wc * (FN * 16) + fn * 16 + (lane & 15);
            #pragma unroll
            for (int r = 0; r < 4; ++r) {
                if (EPI == 2) C[(size_t)(row + r) * ldc + col] += acc[fm][fn][r];
                else          Cb[(size_t)(row + r) * ldc + col] = f2bf(acc[fm][fn][r]);
            }
        }
}

// -------- conv+SiLU: u = silu(conv(xi)+cb), bf16 out ------------------------
__global__ void conv_bf_kernel(const unsigned short* __restrict__ xi,
                               const float* __restrict__ cw,
                               const float* __restrict__ cb,
                               unsigned short* __restrict__ u) {
    int g = blockIdx.x * blockDim.x + threadIdx.x;  // M*1024
    int d = g & (D_INNER - 1);
    int m = g >> 10;
    int l = m & (SEQ_L - 1);
    float4 w = *(const float4*)&cw[d * 4];
    const unsigned short* col = &xi[(size_t)m * 2048 + d];
    float x3 = bf2f(col[0]);
    float x2 = (l >= 1) ? bf2f(col[-2048]) : 0.f;
    float x1 = (l >= 2) ? bf2f(col[-4096]) : 0.f;
    float x0 = (l >= 3) ? bf2f(col[-6144]) : 0.f;
    u[g] = f2bf(silu_f(cb[d] + w.x*x0 + w.y*x1 + w.z*x2 + w.w*x3));
}

// -------- x_proj: xdbl[M,64] = u[M,1024] @ xp_w, f32 ------------------------
__global__ __launch_bounds__(256) void xproj_kernel(const unsigned short* __restrict__ u,
                                                    const float* __restrict__ Bw,
                                                    float* __restrict__ Cc) {
    __shared__ float Bsh[64][68];
    __shared__ float Ash[4][64];
    int row0 = blockIdx.x * 4;
    int t = threadIdx.x;
    int tr = t >> 6, c = t & 63;
    int kk = t >> 2, cb4 = (t & 3) << 4;
    float acc = 0.f;
    for (int k0 = 0; k0 < 1024; k0 += 64) {
        __syncthreads();
        #pragma unroll
        for (int j = 0; j < 4; ++j) {
            float4 v = *(const float4*)&Bw[(size_t)(k0 + kk) * 64 + cb4 + j * 4];
            *(float4*)&Bsh[kk][cb4 + j * 4] = v;
        }
        Ash[tr][c] = bf2f(u[(size_t)(row0 + tr) * 1024 + k0 + c]);
        __syncthreads();
        #pragma unroll
        for (int k = 0; k < 64; ++k)
            acc = fmaf(Ash[tr][k], Bsh[k][c], acc);
    }
    Cc[(size_t)(row0 + tr) * 64 + c] = acc;
}

// -------- dt_proj f32 GEMM (K=32) with softplus epilogue -> delta f32 -------
#define BM 64
#define BN 64
#define BKK 16
__global__ __launch_bounds__(256) void gemm_dt(const float* __restrict__ A,
                                               const float* __restrict__ Bm,
                                               const float* __restrict__ bias,
                                               float* __restrict__ C,
                                               int lda, int ldb, int ldc) {
    __shared__ float As[BM][BKK + 4];
    __shared__ float Bs[BKK][BN];
    int tid = threadIdx.x;
    int n0 = blockIdx.x * BN;
    int m0 = blockIdx.y * BM;
    int tx4 = (tid & 15) << 2;
    int ty4 = (tid >> 4) << 2;
    int arow = tid >> 2, akk = (tid & 3) << 2;
    int brow = tid >> 4, bcol = (tid & 15) << 2;
    float acc[4][4] = {};
    for (int k0 = 0; k0 < 32; k0 += BKK) {
        float4 av = *(const float4*)&A[(size_t)(m0 + arow) * lda + k0 + akk];
        float4 bv = *(const float4*)&Bm[(size_t)(k0 + brow) * ldb + n0 + bcol];
        *(float4*)&As[arow][akk] = av;
        *(float4*)&Bs[brow][bcol] = bv;
        __syncthreads();
        #pragma unroll
        for (int k = 0; k < BKK; ++k) {
            float a0 = As[ty4 + 0][k];
            float a1 = As[ty4 + 1][k];
            float a2 = As[ty4 + 2][k];
            float a3 = As[ty4 + 3][k];
            float4 b = *(float4*)&Bs[k][tx4];
            acc[0][0] = fmaf(a0, b.x, acc[0][0]); acc[0][1] = fmaf(a0, b.y, acc[0][1]);
            acc[0][2] = fmaf(a0, b.z, acc[0][2]); acc[0][3] = fmaf(a0, b.w, acc[0][3]);
            acc[1][0] = fmaf(a1, b.x, acc[1][0]); acc[1][1] = fmaf(a1, b.y, acc[1][1]);
            acc[1][2] = fmaf(a1, b.z, acc[1][2]); acc[1][3] = fmaf(a1, b.w, acc[1][3]);
            acc[2][0] = fmaf(a2, b.x, acc[2][0]); acc[2][1] = fmaf(a2, b.y, acc[2][1]);
            acc[2][2] = fmaf(a2, b.z, acc[2][2]); acc[2][3] = fmaf(a2, b.w, acc[2][3]);
            acc[3][0] = fmaf(a3, b.x, acc[3][0]); acc[3][1] = fmaf(a3, b.y, acc[3][1]);
            acc[3][2] = fmaf(a3, b.z, acc[3][2]); acc[3][3] = fmaf(a3, b.w, acc[3][3]);
        }
        __syncthreads();
    }
    #pragma unroll
    for (int i = 0; i < 4; ++i) {
        int m = m0 + ty4 + i;
        float4 bb = *(const float4*)&bias[n0 + tx4];
        float4 v = make_float4(softplus_f(acc[i][0] + bb.x), softplus_f(acc[i][1] + bb.y),
                               softplus_f(acc[i][2] + bb.z), softplus_f(acc[i][3] + bb.w));
        *(float4*)&C[(size_t)m * ldc + n0 + tx4] = v;
    }
}

// ======================= chunk-parallel selective scan (NC=32) ==============
__global__ __launch_bounds__(256) void scan_p1i(const unsigned short* __restrict__ u,
                                                const float* __restrict__ delta,
                                                const float* __restrict__ xdbl,
                                                const float* __restrict__ A_log,
                                                float* __restrict__ aprod,
                                                float* __restrict__ hloc) {
    int tid = threadIdx.x;
    int d = blockIdx.x * 256 + tid;
    int b = blockIdx.y, c = blockIdx.z;
    int l0 = c * LC;
    __shared__ float sBC[LC][32];
    for (int i = tid; i < LC * 32; i += 256) {
        int l = i >> 5, j = i & 31;
        sBC[l][j] = xdbl[(size_t)(b * SEQ_L + l0 + l) * 64 + 32 + j];
    }
    __syncthreads();
    float A_[D_STATE], h[D_STATE], ap[D_STATE];
    #pragma unroll
    for (int n = 0; n < D_STATE; ++n) {
        A_[n] = -__expf(A_log[(size_t)d * D_STATE + n]);
        h[n] = 0.f; ap[n] = 1.f;
    }
    const unsigned short* ucol = u + (size_t)(b * SEQ_L + l0) * D_INNER + d;
    const float* dcol = delta + (size_t)(b * SEQ_L + l0) * D_INNER + d;
    for (int l = 0; l < LC; ++l) {
        float dtv = dcol[l * D_INNER];
        float uu = bf2f(ucol[l * D_INNER]);
        float du = dtv * uu;
        #pragma unroll
        for (int n = 0; n < D_STATE; ++n) {
            float e = __expf(dtv * A_[n]);
            h[n] = fmaf(e, h[n], du * sBC[l][n]);
            ap[n] *= e;
        }
    }
    #pragma unroll
    for (int n = 0; n < D_STATE; ++n) {
        size_t o = (((size_t)b * NC + c) * D_STATE + n) * D_INNER + d;
        aprod[o] = ap[n];
        hloc[o] = h[n];
    }
}

__global__ __launch_bounds__(256) void scan_p2(const float* __restrict__ aprod,
                                               float* __restrict__ hloc) {
    int d = blockIdx.x * 256 + threadIdx.x;
    int n = blockIdx.y;
    int b = blockIdx.z;
    float h = 0.f;
    #pragma unroll 4
    for (int c = 0; c < NC; ++c) {
        size_t o = (((size_t)b * NC + c) * D_STATE + n) * D_INNER + d;
        float ap = aprod[o];
        float lc = hloc[o];
        hloc[o] = h;
        h = fmaf(ap, h, lc);
    }
}

__global__ __launch_bounds__(256) void scan_p3i(const unsigned short* __restrict__ u,
                                                const float* __restrict__ delta,
                                                const float* __restrict__ xdbl,
                                                const float* __restrict__ A_log,
                                                const float* __restrict__ Dp,
                                                const float* __restrict__ hinit,
                                                const unsigned short* __restrict__ xi,
                                                unsigned short* __restrict__ y) {
    int tid = threadIdx.x;
    int d = blockIdx.x * 256 + tid;
    int b = blockIdx.y, c = blockIdx.z;
    int l0 = c * LC;
    __shared__ float sBC[LC][32];
    for (int i = tid; i < LC * 32; i += 256) {
        int l = i >> 5, j = i & 31;
        sBC[l][j] = xdbl[(size_t)(b * SEQ_L + l0 + l) * 64 + 32 + j];
    }
    __syncthreads();
    float A_[D_STATE], h[D_STATE];
    #pragma unroll
    for (int n = 0; n < D_STATE; ++n) {
        A_[n] = -__expf(A_log[(size_t)d * D_STATE + n]);
        size_t o = (((size_t)b * NC + c) * D_STATE + n) * D_INNER + d;
        h[n] = hinit[o];
    }
    float Dd = Dp[d];
    const unsigned short* ucol = u  + (size_t)(b * SEQ_L + l0) * D_INNER + d;
    const float* dcol = delta + (size_t)(b * SEQ_L + l0) * D_INNER + d;
    const unsigned short* rcol = xi + (size_t)(b * SEQ_L + l0) * 2048 + 1024 + d;
    for (int l = 0; l < LC; ++l) {
        float dtv = dcol[l * D_INNER];
        float uu = bf2f(ucol[l * D_INNER]);
        float du = dtv * uu;
        float yv = 0.f;
        #pragma unroll
        for (int n = 0; n < D_STATE; ++n) {
            float e = __expf(dtv * A_[n]);
            h[n] = fmaf(e, h[n], du * sBC[l][n]);
            yv = fmaf(h[n], sBC[l][16 + n], yv);
        }
        yv = fmaf(uu, Dd, yv);
        float res = bf2f(rcol[l * 2048]);
        y[(size_t)(b * SEQ_L + l0 + l) * D_INNER + d] = f2bf(yv * silu_f(res));
    }
}

// ============== fused final rmsnorm + mean-pool (chunked over L) ============
__global__ __launch_bounds__(256) void rms_pool1(const float* __restrict__ x,
                                                 float* __restrict__ partial) {
    int blk = blockIdx.x;
    int b = blk >> 5, c = blk & 31;
    int wave = threadIdx.x >> 6, lane = threadIdx.x & 63;
    int row0 = b * SEQ_L + c * 32 + wave * 8;
    float4 a0 = make_float4(0.f, 0.f, 0.f, 0.f);
    float4 a1 = make_float4(0.f, 0.f, 0.f, 0.f);
    for (int r = 0; r < 8; ++r) {
        const float* xp = x + (size_t)(row0 + r) * D_MODEL;
        float4 v0 = *(const float4*)&xp[lane * 4];
        float4 v1 = *(const float4*)&xp[256 + lane * 4];
        float ss = v0.x*v0.x + v0.y*v0.y + v0.z*v0.z + v0.w*v0.w
                 + v1.x*v1.x + v1.y*v1.y + v1.z*v1.z + v1.w*v1.w;
        #pragma unroll
        for (int off = 32; off > 0; off >>= 1) ss += __shfl_xor(ss, off);
        float s = rsqrtf(ss * (1.f / D_MODEL) + 1e-5f);
        a0.x = fmaf(v0.x, s, a0.x); a0.y = fmaf(v0.y, s, a0.y);
        a0.z = fmaf(v0.z, s, a0.z); a0.w = fmaf(v0.w, s, a0.w);
        a1.x = fmaf(v1.x, s, a1.x); a1.y = fmaf(v1.y, s, a1.y);
        a1.z = fmaf(v1.z, s, a1.z); a1.w = fmaf(v1.w, s, a1.w);
    }
    __shared__ float red[4][512];
    *(float4*)&red[wave][lane * 4] = a0;
    *(float4*)&red[wave][256 + lane * 4] = a1;
    __syncthreads();
    int d = threadIdx.x * 2;
    float s0 = red[0][d] + red[1][d] + red[2][d] + red[3][d];
    float s1 = red[0][d+1] + red[1][d+1] + red[2][d+1] + red[3][d+1];
    partial[(size_t)blk * 512 + d]     = s0;
    partial[(size_t)blk * 512 + d + 1] = s1;
}

// ---- tail2: pool-reduce + w-scale, emb projection + bias, logits (1 block) -
__global__ __launch_bounds__(512) void tail2_kernel(const float* __restrict__ ppart,
                                                    const float* __restrict__ w,
                                                    const float* __restrict__ pw,
                                                    const float* __restrict__ pb,
                                                    const float* __restrict__ cw,
                                                    const float* __restrict__ cb,
                                                    float* __restrict__ out) {
    __shared__ float sp[2][512];
    __shared__ float se[2][256];
    int t = threadIdx.x;
    {
        int b = t >> 8, dp = (t & 255) * 2;
        float s0 = 0.f, s1 = 0.f;
        #pragma unroll 8
        for (int c = 0; c < 32; ++c) {
            const float* pp = &ppart[((size_t)b * 32 + c) * 512 + dp];
            s0 += pp[0]; s1 += pp[1];
        }
        sp[b][dp]     = s0 * (1.f / SEQ_L) * w[dp];
        sp[b][dp + 1] = s1 * (1.f / SEQ_L) * w[dp + 1];
    }
    __syncthreads();
    {
        int b = t >> 8, e = t & 255;
        float acc = pb[e];
        #pragma unroll 8
        for (int k = 0; k < 512; ++k)
            acc = fmaf(sp[b][k], pw[(size_t)k * 256 + e], acc);
        out[14 + b * 256 + e] = acc;
        se[b][e] = acc;
    }
    __syncthreads();
    {
        int wave = t >> 6, lane = t & 63;
        for (int idx = wave; idx < 14; idx += 8) {
            int bb = idx / 7, cc = idx % 7;
            float a = 0.f;
            #pragma unroll
            for (int i = 0; i < 4; ++i) {
                int k = lane + i * 64;
                a = fmaf(se[bb][k], cw[k * 7 + cc], a);
            }
            #pragma unroll
            for (int off = 32; off > 0; off >>= 1) a += __shfl_xor(a, off);
            if (lane == 0) out[bb * 7 + cc] = a + cb[cc];
        }
    }
}

extern "C" void kernel_launch(void* const* d_in, const int* in_sizes, int n_in,
                              void* d_out, int out_size, void* d_ws, size_t ws_size,
                              hipStream_t stream) {
    const int*   ids    = (const int*)d_in[0];
    const float* emb    = (const float*)d_in[1];
    const float* norm_w = (const float*)d_in[2];
    const float* in_w   = (const float*)d_in[3];
    const float* conv_w = (const float*)d_in[4];
    const float* conv_b = (const float*)d_in[5];
    const float* xp_w   = (const float*)d_in[6];
    const float* dt_w   = (const float*)d_in[7];
    const float* dt_b   = (const float*)d_in[8];
    const float* A_log  = (const float*)d_in[9];
    const float* Dp     = (const float*)d_in[10];
    const float* out_w  = (const float*)d_in[11];
    const float* normf  = (const float*)d_in[12];
    const float* proj_w = (const float*)d_in[13];
    const float* proj_b = (const float*)d_in[14];
    const float* cls_w  = (const float*)d_in[15];
    const float* cls_b  = (const float*)d_in[16];
    float* out = (float*)d_out;

    float* p = (float*)d_ws;
    float* x      = p; p += 1 << 20;          // [2048][512] f32
    float* xnr    = p; p += 1 << 20;          // xn_bf / ppart
    float* xrr    = p; p += 2 << 20;          // xr_bf [2048][2048] bf16
    float* urr    = p; p += 1 << 20;          // u_bf  [2048][1024] bf16
    float* deltab = p; p += 2 << 20;          // delta [2048][1024] f32
    float* xdbl   = p; p += 1 << 17;          // [2048][64] f32
    float* wreg   = p; p += 1572864;          // in_wt x2 + out_wt x2 (bf16)
    float* aprod  = p; p += 2 << 20;          // state (NC=32 uses half)
    float* hloc   = p; p += 2 << 20;          // state
    float* ybr    = p; p += 1 << 20;          // yb_bf [2048][1024] bf16

    unsigned short* xn_bf  = (unsigned short*)xnr;
    float*          ppart  = xnr;
    unsigned short* xr_bf  = (unsigned short*)xrr;
    unsigned short* u_bf   = (unsigned short*)urr;
    unsigned short* in_wt_all  = (unsigned short*)wreg;
    unsigned short* out_wt_all = (unsigned short*)(wreg + (1 << 20));
    unsigned short* yb_bf  = (unsigned short*)ybr;

    init_kernel<<<dim3(64, 32, 5), 256, 0, stream>>>(
        ids, emb, norm_w, in_w, out_w, x, xn_bf, in_wt_all, out_wt_all);

    for (int i = 0; i < NLAYER; ++i) {
        unsigned short* in_wt  = in_wt_all  + (size_t)i * 2048 * 512;
        unsigned short* out_wt = out_wt_all + (size_t)i * 512 * 1024;
        const float* cwi  = conv_w + (size_t)i * D_INNER * 4;
        const float* cbi  = conv_b + (size_t)i * D_INNER;
        const float* dtwi = dt_w + (size_t)i * DT_RANK * D_INNER;
        const float* dtbi = dt_b + (size_t)i * D_INNER;
        const float* Ali  = A_log + (size_t)i * D_INNER * D_STATE;
        const float* Dpi  = Dp + (size_t)i * D_INNER;

        if (i > 0)
            rmsnorm_bf_kernel<<<M_ROWS, 64, 0, stream>>>(x, norm_w + i * D_MODEL, xn_bf);
        gemm_mfma_t<128, 64, 3><<<dim3(2048 / 64, M_ROWS / 128), 256, 0, stream>>>(
            xn_bf, in_wt, nullptr, xr_bf, 512, 2048);
        conv_bf_kernel<<<(M_ROWS * D_INNER) / 256, 256, 0, stream>>>(
            xr_bf, cwi, cbi, u_bf);
        xproj_kernel<<<M_ROWS / 4, 256, 0, stream>>>(
            u_bf, xp_w + (size_t)i * D_INNER * 64, xdbl);
        gemm_dt<<<dim3(1024 / BN, M_ROWS / BM), 256, 0, stream>>>(
            xdbl, dtwi, dtbi, deltab, 64, 1024, 1024);
        scan_p1i<<<dim3(4, BATCH, NC), 256, 0, stream>>>(
            u_bf, deltab, xdbl, Ali, aprod, hloc);
        scan_p2<<<dim3(4, D_STATE, BATCH), 256, 0, stream>>>(aprod, hloc);
        scan_p3i<<<dim3(4, BATCH, NC), 256, 0, stream>>>(
            u_bf, deltab, xdbl, Ali, Dpi, hloc, xr_bf, yb_bf);
        gemm_mfma_t<64, 32, 2><<<dim3(512 / 32, M_ROWS / 64), 256, 0, stream>>>(
            yb_bf, out_wt, x, nullptr, 1024, 512);
    }

    rms_pool1<<<BATCH * 32, 256, 0, stream>>>(x, ppart);
    tail2_kernel<<<1, 512, 0, stream>>>(ppart, normf, proj_w, proj_b, cls_w, cls_b, out);
}

// Round 17
// 242.411 us; speedup vs baseline: 1.0658x; 1.0658x over previous
//
#include <hip/hip_runtime.h>
#include <cstddef>

#define D_MODEL   512
#define D_INNER   1024
#define D_STATE   16
#define DT_RANK   32
#define SEQ_L     1024
#define BATCH     2
#define NLAYER    2
#define M_ROWS    (BATCH * SEQ_L)   // 2048
#define NC        64                // scan chunks (64 = measured best)
#define LC        (SEQ_L / NC)      // 16 timesteps per chunk

typedef __bf16 bf16x8 __attribute__((ext_vector_type(8)));
typedef float  f32x4  __attribute__((ext_vector_type(4)));

__device__ __forceinline__ float softplus_f(float x) {
    return fmaxf(x, 0.f) + log1pf(expf(-fabsf(x)));
}
__device__ __forceinline__ float silu_f(float x) {
    return x / (1.f + __expf(-x));
}
__device__ __forceinline__ unsigned short f2bf(float f) {
    unsigned u = __float_as_uint(f);
    return (unsigned short)((u + 0x7fffu + ((u >> 16) & 1u)) >> 16);
}
__device__ __forceinline__ float bf2f(unsigned short v) {
    return __uint_as_float(((unsigned)v) << 16);
}
__device__ __forceinline__ unsigned pack_bf2(float lo, float hi) {
    return (unsigned)f2bf(lo) | ((unsigned)f2bf(hi) << 16);
}

// ==== init: embed gather + layer-0 rmsnorm + both weight cast-transposes ====
__global__ __launch_bounds__(256) void init_kernel(const int* __restrict__ ids,
                                                   const float* __restrict__ emb,
                                                   const float* __restrict__ nw0,
                                                   const float* __restrict__ in_w,
                                                   const float* __restrict__ out_w,
                                                   float* __restrict__ x,
                                                   unsigned short* __restrict__ xn_bf,
                                                   unsigned short* __restrict__ in_wt_all,
                                                   unsigned short* __restrict__ out_wt_all) {
    int z = blockIdx.z;
    if (z == 4) {                                   // embed + layer-0 rmsnorm
        int blk = blockIdx.y * 64 + blockIdx.x;
        if (blk >= 512) return;
        int wave = threadIdx.x >> 6, lane = threadIdx.x & 63;
        int m = blk * 4 + wave;
        int row = ids[m];
        const float* ep = emb + (size_t)row * D_MODEL;
        float4 v0 = *(const float4*)&ep[lane * 4];
        float4 v1 = *(const float4*)&ep[256 + lane * 4];
        float* xp = x + (size_t)m * D_MODEL;
        *(float4*)&xp[lane * 4] = v0;
        *(float4*)&xp[256 + lane * 4] = v1;
        float ss = v0.x*v0.x + v0.y*v0.y + v0.z*v0.z + v0.w*v0.w
                 + v1.x*v1.x + v1.y*v1.y + v1.z*v1.z + v1.w*v1.w;
        #pragma unroll
        for (int off = 32; off > 0; off >>= 1) ss += __shfl_xor(ss, off);
        float scale = rsqrtf(ss * (1.f / D_MODEL) + 1e-5f);
        float4 w0 = *(const float4*)&nw0[lane * 4];
        float4 w1 = *(const float4*)&nw0[256 + lane * 4];
        unsigned short* op = xn_bf + (size_t)m * D_MODEL;
        uint2 p0, p1;
        p0.x = pack_bf2(v0.x * scale * w0.x, v0.y * scale * w0.y);
        p0.y = pack_bf2(v0.z * scale * w0.z, v0.w * scale * w0.w);
        p1.x = pack_bf2(v1.x * scale * w1.x, v1.y * scale * w1.y);
        p1.y = pack_bf2(v1.z * scale * w1.z, v1.w * scale * w1.w);
        *(uint2*)&op[lane * 4] = p0;
        *(uint2*)&op[256 + lane * 4] = p1;
        return;
    }
    const float* W; unsigned short* Wt; int K, N;
    if (z < 2) {
        if (blockIdx.x >= 64 || blockIdx.y >= 16) return;
        W = in_w + (size_t)z * 512 * 2048; Wt = in_wt_all + (size_t)z * 2048 * 512;
        K = 512; N = 2048;
    } else {
        int zz = z - 2;
        if (blockIdx.x >= 16 || blockIdx.y >= 32) return;
        W = out_w + (size_t)zz * 1024 * 512; Wt = out_wt_all + (size_t)zz * 512 * 1024;
        K = 1024; N = 512;
    }
    __shared__ float tile[32][33];
    int n0 = blockIdx.x * 32, k0 = blockIdx.y * 32;
    int tx = threadIdx.x & 31, ty = threadIdx.x >> 5;
    #pragma unroll
    for (int i = 0; i < 4; ++i)
        tile[ty + i*8][tx] = W[(size_t)(k0 + ty + i*8) * N + n0 + tx];
    __syncthreads();
    #pragma unroll
    for (int i = 0; i < 4; ++i)
        Wt[(size_t)(n0 + ty + i*8) * K + k0 + tx] = f2bf(tile[tx][ty + i*8]);
}

// -------- rmsnorm (bf16 out), layer >= 1 ------------------------------------
__global__ __launch_bounds__(64) void rmsnorm_bf_kernel(const float* __restrict__ x,
                                                        const float* __restrict__ w,
                                                        unsigned short* __restrict__ out) {
    int row = blockIdx.x;
    int tid = threadIdx.x;
    const float* xp = x + (size_t)row * D_MODEL;
    float4 v0 = *(const float4*)&xp[tid * 4];
    float4 v1 = *(const float4*)&xp[256 + tid * 4];
    float ss = v0.x*v0.x + v0.y*v0.y + v0.z*v0.z + v0.w*v0.w
             + v1.x*v1.x + v1.y*v1.y + v1.z*v1.z + v1.w*v1.w;
    #pragma unroll
    for (int off = 32; off > 0; off >>= 1) ss += __shfl_xor(ss, off);
    float scale = rsqrtf(ss * (1.f / D_MODEL) + 1e-5f);
    float4 w0 = *(const float4*)&w[tid * 4];
    float4 w1 = *(const float4*)&w[256 + tid * 4];
    unsigned short* op = out + (size_t)row * D_MODEL;
    uint2 p0, p1;
    p0.x = pack_bf2(v0.x * scale * w0.x, v0.y * scale * w0.y);
    p0.y = pack_bf2(v0.z * scale * w0.z, v0.w * scale * w0.w);
    p1.x = pack_bf2(v1.x * scale * w1.x, v1.y * scale * w1.y);
    p1.y = pack_bf2(v1.z * scale * w1.z, v1.w * scale * w1.w);
    *(uint2*)&op[tid * 4] = p0;
    *(uint2*)&op[256 + tid * 4] = p1;
}

// ===== templated bf16 MFMA GEMM =============================================
template<int BMT, int BNT, int EPI>
__global__ __launch_bounds__(256) void gemm_mfma_t(const unsigned short* __restrict__ A,
                                                   const unsigned short* __restrict__ Bt,
                                                   float* __restrict__ C,
                                                   unsigned short* __restrict__ Cb,
                                                   int K, int ldc) {
    constexpr int FM = BMT / 32;
    constexpr int FN = BNT / 32;
    __shared__ unsigned short As[BMT * 64];
    __shared__ unsigned short Bs[BNT * 64];
    int m0 = blockIdx.y * BMT;
    int n0 = blockIdx.x * BNT;
    int t = threadIdx.x;
    int lane = t & 63, wave = t >> 6;
    int wr = wave >> 1, wc = wave & 1;
    int srow = t >> 3;
    int sc8  = t & 7;
    f32x4 acc[FM][FN] = {};

    for (int k0 = 0; k0 < K; k0 += 64) {
        __syncthreads();
        #pragma unroll
        for (int i = 0; i < BMT / 32; ++i) {
            int row = i * 32 + srow;
            int csrc = sc8 ^ (row & 7);
            __builtin_amdgcn_global_load_lds(
                (const __attribute__((address_space(1))) void*)
                    &A[(size_t)(m0 + row) * K + k0 + csrc * 8],
                (__attribute__((address_space(3))) void*)
                    &As[row * 64 + sc8 * 8], 16, 0, 0);
        }
        #pragma unroll
        for (int i = 0; i < BNT / 32; ++i) {
            int row = i * 32 + srow;
            int csrc = sc8 ^ (row & 7);
            __builtin_amdgcn_global_load_lds(
                (const __attribute__((address_space(1))) void*)
                    &Bt[(size_t)(n0 + row) * K + k0 + csrc * 8],
                (__attribute__((address_space(3))) void*)
                    &Bs[row * 64 + sc8 * 8], 16, 0, 0);
        }
        __syncthreads();
        #pragma unroll
        for (int ks = 0; ks < 2; ++ks) {
            bf16x8 av[FM], bv[FN];
            #pragma unroll
            for (int f = 0; f < FM; ++f) {
                int ar = wr * (FM * 16) + f * 16 + (lane & 15);
                int ac = (ks * 4 + (lane >> 4)) ^ (ar & 7);
                av[f] = *reinterpret_cast<const bf16x8*>(&As[ar * 64 + ac * 8]);
            }
            #pragma unroll
            for (int f = 0; f < FN; ++f) {
                int br = wc * (FN * 16) + f * 16 + (lane & 15);
                int bc = (ks * 4 + (lane >> 4)) ^ (br & 7);
                bv[f] = *reinterpret_cast<const bf16x8*>(&Bs[br * 64 + bc * 8]);
            }
            #pragma unroll
            for (int fm = 0; fm < FM; ++fm)
                #pragma unroll
                for (int fn = 0; fn < FN; ++fn)
                    acc[fm][fn] = __builtin_amdgcn_mfma_f32_16x16x32_bf16(
                        av[fm], bv[fn], acc[fm][fn], 0, 0, 0);
        }
    }
    #pragma unroll
    for (int fm = 0; fm < FM; ++fm)
        #pragma unroll
        for (int fn = 0; fn < FN; ++fn) {
            int row = m0 + wr * (FM * 16) + fm * 16 + (lane >> 4) * 4;
            int col = n0 + wc * (FN * 16) + fn * 16 + (lane & 15);
            #pragma unroll
            for (int r = 0; r < 4; ++r) {
                if (EPI == 2) C[(size_t)(row + r) * ldc + col] += acc[fm][fn][r];
                else          Cb[(size_t)(row + r) * ldc + col] = f2bf(acc[fm][fn][r]);
            }
        }
}

// -------- conv+SiLU: u = silu(conv(xi)+cb), bf16 out ------------------------
__global__ void conv_bf_kernel(const unsigned short* __restrict__ xi,
                               const float* __restrict__ cw,
                               const float* __restrict__ cb,
                               unsigned short* __restrict__ u) {
    int g = blockIdx.x * blockDim.x + threadIdx.x;  // M*1024
    int d = g & (D_INNER - 1);
    int m = g >> 10;
    int l = m & (SEQ_L - 1);
    float4 w = *(const float4*)&cw[d * 4];
    const unsigned short* col = &xi[(size_t)m * 2048 + d];
    float x3 = bf2f(col[0]);
    float x2 = (l >= 1) ? bf2f(col[-2048]) : 0.f;
    float x1 = (l >= 2) ? bf2f(col[-4096]) : 0.f;
    float x0 = (l >= 3) ? bf2f(col[-6144]) : 0.f;
    u[g] = f2bf(silu_f(cb[d] + w.x*x0 + w.y*x1 + w.z*x2 + w.w*x3));
}

// -------- x_proj: xdbl[M,64] = u[M,1024] @ xp_w, f32 ------------------------
__global__ __launch_bounds__(256) void xproj_kernel(const unsigned short* __restrict__ u,
                                                    const float* __restrict__ Bw,
                                                    float* __restrict__ Cc) {
    __shared__ float Bsh[64][68];
    __shared__ float Ash[4][64];
    int row0 = blockIdx.x * 4;
    int t = threadIdx.x;
    int tr = t >> 6, c = t & 63;
    int kk = t >> 2, cb4 = (t & 3) << 4;
    float acc = 0.f;
    for (int k0 = 0; k0 < 1024; k0 += 64) {
        __syncthreads();
        #pragma unroll
        for (int j = 0; j < 4; ++j) {
            float4 v = *(const float4*)&Bw[(size_t)(k0 + kk) * 64 + cb4 + j * 4];
            *(float4*)&Bsh[kk][cb4 + j * 4] = v;
        }
        Ash[tr][c] = bf2f(u[(size_t)(row0 + tr) * 1024 + k0 + c]);
        __syncthreads();
        #pragma unroll
        for (int k = 0; k < 64; ++k)
            acc = fmaf(Ash[tr][k], Bsh[k][c], acc);
    }
    Cc[(size_t)(row0 + tr) * 64 + c] = acc;
}

// -------- dt_proj f32 GEMM (K=32) with softplus epilogue -> delta f32 -------
#define BM 64
#define BN 64
#define BKK 16
__global__ __launch_bounds__(256) void gemm_dt(const float* __restrict__ A,
                                               const float* __restrict__ Bm,
                                               const float* __restrict__ bias,
                                               float* __restrict__ C,
                                               int lda, int ldb, int ldc) {
    __shared__ float As[BM][BKK + 4];
    __shared__ float Bs[BKK][BN];
    int tid = threadIdx.x;
    int n0 = blockIdx.x * BN;
    int m0 = blockIdx.y * BM;
    int tx4 = (tid & 15) << 2;
    int ty4 = (tid >> 4) << 2;
    int arow = tid >> 2, akk = (tid & 3) << 2;
    int brow = tid >> 4, bcol = (tid & 15) << 2;
    float acc[4][4] = {};
    for (int k0 = 0; k0 < 32; k0 += BKK) {
        float4 av = *(const float4*)&A[(size_t)(m0 + arow) * lda + k0 + akk];
        float4 bv = *(const float4*)&Bm[(size_t)(k0 + brow) * ldb + n0 + bcol];
        *(float4*)&As[arow][akk] = av;
        *(float4*)&Bs[brow][bcol] = bv;
        __syncthreads();
        #pragma unroll
        for (int k = 0; k < BKK; ++k) {
            float a0 = As[ty4 + 0][k];
            float a1 = As[ty4 + 1][k];
            float a2 = As[ty4 + 2][k];
            float a3 = As[ty4 + 3][k];
            float4 b = *(float4*)&Bs[k][tx4];
            acc[0][0] = fmaf(a0, b.x, acc[0][0]); acc[0][1] = fmaf(a0, b.y, acc[0][1]);
            acc[0][2] = fmaf(a0, b.z, acc[0][2]); acc[0][3] = fmaf(a0, b.w, acc[0][3]);
            acc[1][0] = fmaf(a1, b.x, acc[1][0]); acc[1][1] = fmaf(a1, b.y, acc[1][1]);
            acc[1][2] = fmaf(a1, b.z, acc[1][2]); acc[1][3] = fmaf(a1, b.w, acc[1][3]);
            acc[2][0] = fmaf(a2, b.x, acc[2][0]); acc[2][1] = fmaf(a2, b.y, acc[2][1]);
            acc[2][2] = fmaf(a2, b.z, acc[2][2]); acc[2][3] = fmaf(a2, b.w, acc[2][3]);
            acc[3][0] = fmaf(a3, b.x, acc[3][0]); acc[3][1] = fmaf(a3, b.y, acc[3][1]);
            acc[3][2] = fmaf(a3, b.z, acc[3][2]); acc[3][3] = fmaf(a3, b.w, acc[3][3]);
        }
        __syncthreads();
    }
    #pragma unroll
    for (int i = 0; i < 4; ++i) {
        int m = m0 + ty4 + i;
        float4 bb = *(const float4*)&bias[n0 + tx4];
        float4 v = make_float4(softplus_f(acc[i][0] + bb.x), softplus_f(acc[i][1] + bb.y),
                               softplus_f(acc[i][2] + bb.z), softplus_f(acc[i][3] + bb.w));
        *(float4*)&C[(size_t)m * ldc + n0 + tx4] = v;
    }
}

// ======================= chunk-parallel selective scan (NC=64) ==============
__global__ __launch_bounds__(256) void scan_p1i(const unsigned short* __restrict__ u,
                                                const float* __restrict__ delta,
                                                const float* __restrict__ xdbl,
                                                const float* __restrict__ A_log,
                                                float* __restrict__ aprod,
                                                float* __restrict__ hloc) {
    int tid = threadIdx.x;
    int d = blockIdx.x * 256 + tid;
    int b = blockIdx.y, c = blockIdx.z;
    int l0 = c * LC;
    __shared__ float sBC[LC][32];
    for (int i = tid; i < LC * 32; i += 256) {
        int l = i >> 5, j = i & 31;
        sBC[l][j] = xdbl[(size_t)(b * SEQ_L + l0 + l) * 64 + 32 + j];
    }
    __syncthreads();
    float A_[D_STATE], h[D_STATE], ap[D_STATE];
    #pragma unroll
    for (int n = 0; n < D_STATE; ++n) {
        A_[n] = -__expf(A_log[(size_t)d * D_STATE + n]);
        h[n] = 0.f; ap[n] = 1.f;
    }
    const unsigned short* ucol = u + (size_t)(b * SEQ_L + l0) * D_INNER + d;
    const float* dcol = delta + (size_t)(b * SEQ_L + l0) * D_INNER + d;
    for (int l = 0; l < LC; ++l) {
        float dtv = dcol[l * D_INNER];
        float uu = bf2f(ucol[l * D_INNER]);
        float du = dtv * uu;
        #pragma unroll
        for (int n = 0; n < D_STATE; ++n) {
            float e = __expf(dtv * A_[n]);
            h[n] = fmaf(e, h[n], du * sBC[l][n]);
            ap[n] *= e;
        }
    }
    #pragma unroll
    for (int n = 0; n < D_STATE; ++n) {
        size_t o = (((size_t)b * NC + c) * D_STATE + n) * D_INNER + d;
        aprod[o] = ap[n];
        hloc[o] = h[n];
    }
}

__global__ __launch_bounds__(256) void scan_p2(const float* __restrict__ aprod,
                                               float* __restrict__ hloc) {
    int d = blockIdx.x * 256 + threadIdx.x;
    int n = blockIdx.y;
    int b = blockIdx.z;
    float h = 0.f;
    #pragma unroll 4
    for (int c = 0; c < NC; ++c) {
        size_t o = (((size_t)b * NC + c) * D_STATE + n) * D_INNER + d;
        float ap = aprod[o];
        float lc = hloc[o];
        hloc[o] = h;
        h = fmaf(ap, h, lc);
    }
}

__global__ __launch_bounds__(256) void scan_p3i(const unsigned short* __restrict__ u,
                                                const float* __restrict__ delta,
                                                const float* __restrict__ xdbl,
                                                const float* __restrict__ A_log,
                                                const float* __restrict__ Dp,
                                                const float* __restrict__ hinit,
                                                const unsigned short* __restrict__ xi,
                                                unsigned short* __restrict__ y) {
    int tid = threadIdx.x;
    int d = blockIdx.x * 256 + tid;
    int b = blockIdx.y, c = blockIdx.z;
    int l0 = c * LC;
    __shared__ float sBC[LC][32];
    for (int i = tid; i < LC * 32; i += 256) {
        int l = i >> 5, j = i & 31;
        sBC[l][j] = xdbl[(size_t)(b * SEQ_L + l0 + l) * 64 + 32 + j];
    }
    __syncthreads();
    float A_[D_STATE], h[D_STATE];
    #pragma unroll
    for (int n = 0; n < D_STATE; ++n) {
        A_[n] = -__expf(A_log[(size_t)d * D_STATE + n]);
        size_t o = (((size_t)b * NC + c) * D_STATE + n) * D_INNER + d;
        h[n] = hinit[o];
    }
    float Dd = Dp[d];
    const unsigned short* ucol = u  + (size_t)(b * SEQ_L + l0) * D_INNER + d;
    const float* dcol = delta + (size_t)(b * SEQ_L + l0) * D_INNER + d;
    const unsigned short* rcol = xi + (size_t)(b * SEQ_L + l0) * 2048 + 1024 + d;
    for (int l = 0; l < LC; ++l) {
        float dtv = dcol[l * D_INNER];
        float uu = bf2f(ucol[l * D_INNER]);
        float du = dtv * uu;
        float yv = 0.f;
        #pragma unroll
        for (int n = 0; n < D_STATE; ++n) {
            float e = __expf(dtv * A_[n]);
            h[n] = fmaf(e, h[n], du * sBC[l][n]);
            yv = fmaf(h[n], sBC[l][16 + n], yv);
        }
        yv = fmaf(uu, Dd, yv);
        float res = bf2f(rcol[l * 2048]);
        y[(size_t)(b * SEQ_L + l0 + l) * D_INNER + d] = f2bf(yv * silu_f(res));
    }
}

// ============== fused final rmsnorm + mean-pool (chunked over L) ============
__global__ __launch_bounds__(256) void rms_pool1(const float* __restrict__ x,
                                                 float* __restrict__ partial) {
    int blk = blockIdx.x;
    int b = blk >> 5, c = blk & 31;
    int wave = threadIdx.x >> 6, lane = threadIdx.x & 63;
    int row0 = b * SEQ_L + c * 32 + wave * 8;
    float4 a0 = make_float4(0.f, 0.f, 0.f, 0.f);
    float4 a1 = make_float4(0.f, 0.f, 0.f, 0.f);
    for (int r = 0; r < 8; ++r) {
        const float* xp = x + (size_t)(row0 + r) * D_MODEL;
        float4 v0 = *(const float4*)&xp[lane * 4];
        float4 v1 = *(const float4*)&xp[256 + lane * 4];
        float ss = v0.x*v0.x + v0.y*v0.y + v0.z*v0.z + v0.w*v0.w
                 + v1.x*v1.x + v1.y*v1.y + v1.z*v1.z + v1.w*v1.w;
        #pragma unroll
        for (int off = 32; off > 0; off >>= 1) ss += __shfl_xor(ss, off);
        float s = rsqrtf(ss * (1.f / D_MODEL) + 1e-5f);
        a0.x = fmaf(v0.x, s, a0.x); a0.y = fmaf(v0.y, s, a0.y);
        a0.z = fmaf(v0.z, s, a0.z); a0.w = fmaf(v0.w, s, a0.w);
        a1.x = fmaf(v1.x, s, a1.x); a1.y = fmaf(v1.y, s, a1.y);
        a1.z = fmaf(v1.z, s, a1.z); a1.w = fmaf(v1.w, s, a1.w);
    }
    __shared__ float red[4][512];
    *(float4*)&red[wave][lane * 4] = a0;
    *(float4*)&red[wave][256 + lane * 4] = a1;
    __syncthreads();
    int d = threadIdx.x * 2;
    float s0 = red[0][d] + red[1][d] + red[2][d] + red[3][d];
    float s1 = red[0][d+1] + red[1][d+1] + red[2][d+1] + red[3][d+1];
    partial[(size_t)blk * 512 + d]     = s0;
    partial[(size_t)blk * 512 + d + 1] = s1;
}

// ---- tail2: pool-reduce + w-scale, emb projection + bias, logits (1 block) -
__global__ __launch_bounds__(512) void tail2_kernel(const float* __restrict__ ppart,
                                                    const float* __restrict__ w,
                                                    const float* __restrict__ pw,
                                                    const float* __restrict__ pb,
                                                    const float* __restrict__ cw,
                                                    const float* __restrict__ cb,
                                                    float* __restrict__ out) {
    __shared__ float sp[2][512];
    __shared__ float se[2][256];
    int t = threadIdx.x;
    {
        int b = t >> 8, dp = (t & 255) * 2;
        float s0 = 0.f, s1 = 0.f;
        #pragma unroll 8
        for (int c = 0; c < 32; ++c) {
            const float* pp = &ppart[((size_t)b * 32 + c) * 512 + dp];
            s0 += pp[0]; s1 += pp[1];
        }
        sp[b][dp]     = s0 * (1.f / SEQ_L) * w[dp];
        sp[b][dp + 1] = s1 * (1.f / SEQ_L) * w[dp + 1];
    }
    __syncthreads();
    {
        int b = t >> 8, e = t & 255;
        float acc = pb[e];
        #pragma unroll 8
        for (int k = 0; k < 512; ++k)
            acc = fmaf(sp[b][k], pw[(size_t)k * 256 + e], acc);
        out[14 + b * 256 + e] = acc;
        se[b][e] = acc;
    }
    __syncthreads();
    {
        int wave = t >> 6, lane = t & 63;
        for (int idx = wave; idx < 14; idx += 8) {
            int bb = idx / 7, cc = idx % 7;
            float a = 0.f;
            #pragma unroll
            for (int i = 0; i < 4; ++i) {
                int k = lane + i * 64;
                a = fmaf(se[bb][k], cw[k * 7 + cc], a);
            }
            #pragma unroll
            for (int off = 32; off > 0; off >>= 1) a += __shfl_xor(a, off);
            if (lane == 0) out[bb * 7 + cc] = a + cb[cc];
        }
    }
}

extern "C" void kernel_launch(void* const* d_in, const int* in_sizes, int n_in,
                              void* d_out, int out_size, void* d_ws, size_t ws_size,
                              hipStream_t stream) {
    const int*   ids    = (const int*)d_in[0];
    const float* emb    = (const float*)d_in[1];
    const float* norm_w = (const float*)d_in[2];
    const float* in_w   = (const float*)d_in[3];
    const float* conv_w = (const float*)d_in[4];
    const float* conv_b = (const float*)d_in[5];
    const float* xp_w   = (const float*)d_in[6];
    const float* dt_w   = (const float*)d_in[7];
    const float* dt_b   = (const float*)d_in[8];
    const float* A_log  = (const float*)d_in[9];
    const float* Dp     = (const float*)d_in[10];
    const float* out_w  = (const float*)d_in[11];
    const float* normf  = (const float*)d_in[12];
    const float* proj_w = (const float*)d_in[13];
    const float* proj_b = (const float*)d_in[14];
    const float* cls_w  = (const float*)d_in[15];
    const float* cls_b  = (const float*)d_in[16];
    float* out = (float*)d_out;

    float* p = (float*)d_ws;
    float* x      = p; p += 1 << 20;          // [2048][512] f32
    float* xnr    = p; p += 1 << 20;          // xn_bf / ppart
    float* xrr    = p; p += 2 << 20;          // xr_bf [2048][2048] bf16
    float* urr    = p; p += 1 << 20;          // u_bf  [2048][1024] bf16
    float* deltab = p; p += 2 << 20;          // delta [2048][1024] f32
    float* xdbl   = p; p += 1 << 17;          // [2048][64] f32
    float* wreg   = p; p += 1572864;          // in_wt x2 + out_wt x2 (bf16)
    float* aprod  = p; p += 2 << 20;          // [2][64][16][1024] f32
    float* hloc   = p; p += 2 << 20;          // same shape
    float* ybr    = p; p += 1 << 20;          // yb_bf [2048][1024] bf16

    unsigned short* xn_bf  = (unsigned short*)xnr;
    float*          ppart  = xnr;
    unsigned short* xr_bf  = (unsigned short*)xrr;
    unsigned short* u_bf   = (unsigned short*)urr;
    unsigned short* in_wt_all  = (unsigned short*)wreg;
    unsigned short* out_wt_all = (unsigned short*)(wreg + (1 << 20));
    unsigned short* yb_bf  = (unsigned short*)ybr;

    init_kernel<<<dim3(64, 32, 5), 256, 0, stream>>>(
        ids, emb, norm_w, in_w, out_w, x, xn_bf, in_wt_all, out_wt_all);

    for (int i = 0; i < NLAYER; ++i) {
        unsigned short* in_wt  = in_wt_all  + (size_t)i * 2048 * 512;
        unsigned short* out_wt = out_wt_all + (size_t)i * 512 * 1024;
        const float* cwi  = conv_w + (size_t)i * D_INNER * 4;
        const float* cbi  = conv_b + (size_t)i * D_INNER;
        const float* dtwi = dt_w + (size_t)i * DT_RANK * D_INNER;
        const float* dtbi = dt_b + (size_t)i * D_INNER;
        const float* Ali  = A_log + (size_t)i * D_INNER * D_STATE;
        const float* Dpi  = Dp + (size_t)i * D_INNER;

        if (i > 0)
            rmsnorm_bf_kernel<<<M_ROWS, 64, 0, stream>>>(x, norm_w + i * D_MODEL, xn_bf);
        gemm_mfma_t<128, 64, 3><<<dim3(2048 / 64, M_ROWS / 128), 256, 0, stream>>>(
            xn_bf, in_wt, nullptr, xr_bf, 512, 2048);
        conv_bf_kernel<<<(M_ROWS * D_INNER) / 256, 256, 0, stream>>>(
            xr_bf, cwi, cbi, u_bf);
        xproj_kernel<<<M_ROWS / 4, 256, 0, stream>>>(
            u_bf, xp_w + (size_t)i * D_INNER * 64, xdbl);
        gemm_dt<<<dim3(1024 / BN, M_ROWS / BM), 256, 0, stream>>>(
            xdbl, dtwi, dtbi, deltab, 64, 1024, 1024);
        scan_p1i<<<dim3(4, BATCH, NC), 256, 0, stream>>>(
            u_bf, deltab, xdbl, Ali, aprod, hloc);
        scan_p2<<<dim3(4, D_STATE, BATCH), 256, 0, stream>>>(aprod, hloc);
        scan_p3i<<<dim3(4, BATCH, NC), 256, 0, stream>>>(
            u_bf, deltab, xdbl, Ali, Dpi, hloc, xr_bf, yb_bf);
        gemm_mfma_t<64, 32, 2><<<dim3(512 / 32, M_ROWS / 64), 256, 0, stream>>>(
            yb_bf, out_wt, x, nullptr, 1024, 512);
    }

    rms_pool1<<<BATCH * 32, 256, 0, stream>>>(x, ppart);
    tail2_kernel<<<1, 512, 0, stream>>>(ppart, normf, proj_w, proj_b, cls_w, cls_b, out);
}

// Round 18
// 237.658 us; speedup vs baseline: 1.0871x; 1.0200x over previous
//
#include <hip/hip_runtime.h>
#include <cstddef>

#define D_MODEL   512
#define D_INNER   1024
#define D_STATE   16
#define DT_RANK   32
#define SEQ_L     1024
#define BATCH     2
#define NLAYER    2
#define M_ROWS    (BATCH * SEQ_L)   // 2048
#define NC        64                // scan chunks (measured best)
#define LC        (SEQ_L / NC)      // 16 timesteps per chunk

typedef __bf16 bf16x8 __attribute__((ext_vector_type(8)));
typedef float  f32x4  __attribute__((ext_vector_type(4)));

__device__ __forceinline__ float softplus_f(float x) {
    return fmaxf(x, 0.f) + log1pf(expf(-fabsf(x)));
}
__device__ __forceinline__ float silu_f(float x) {
    return x / (1.f + __expf(-x));
}
__device__ __forceinline__ unsigned short f2bf(float f) {
    unsigned u = __float_as_uint(f);
    return (unsigned short)((u + 0x7fffu + ((u >> 16) & 1u)) >> 16);
}
__device__ __forceinline__ float bf2f(unsigned short v) {
    return __uint_as_float(((unsigned)v) << 16);
}
__device__ __forceinline__ unsigned pack_bf2(float lo, float hi) {
    return (unsigned)f2bf(lo) | ((unsigned)f2bf(hi) << 16);
}

// ==== init (flat 3584-block grid): castT in_w (1024x2) + castT out_w (512x2)
//      + embed+rms0 (512) ================================================
__global__ __launch_bounds__(256) void init_kernel(const int* __restrict__ ids,
                                                   const float* __restrict__ emb,
                                                   const float* __restrict__ nw0,
                                                   const float* __restrict__ in_w,
                                                   const float* __restrict__ out_w,
                                                   float* __restrict__ x,
                                                   unsigned short* __restrict__ xn_bf,
                                                   unsigned short* __restrict__ in_wt_all,
                                                   unsigned short* __restrict__ out_wt_all) {
    int b = blockIdx.x;
    if (b >= 3072) {                                // embed + layer-0 rmsnorm
        int blk = b - 3072;                         // 0..511, 4 rows each
        int wave = threadIdx.x >> 6, lane = threadIdx.x & 63;
        int m = blk * 4 + wave;
        int row = ids[m];
        const float* ep = emb + (size_t)row * D_MODEL;
        float4 v0 = *(const float4*)&ep[lane * 4];
        float4 v1 = *(const float4*)&ep[256 + lane * 4];
        float* xp = x + (size_t)m * D_MODEL;
        *(float4*)&xp[lane * 4] = v0;
        *(float4*)&xp[256 + lane * 4] = v1;
        float ss = v0.x*v0.x + v0.y*v0.y + v0.z*v0.z + v0.w*v0.w
                 + v1.x*v1.x + v1.y*v1.y + v1.z*v1.z + v1.w*v1.w;
        #pragma unroll
        for (int off = 32; off > 0; off >>= 1) ss += __shfl_xor(ss, off);
        float scale = rsqrtf(ss * (1.f / D_MODEL) + 1e-5f);
        float4 w0 = *(const float4*)&nw0[lane * 4];
        float4 w1 = *(const float4*)&nw0[256 + lane * 4];
        unsigned short* op = xn_bf + (size_t)m * D_MODEL;
        uint2 p0, p1;
        p0.x = pack_bf2(v0.x * scale * w0.x, v0.y * scale * w0.y);
        p0.y = pack_bf2(v0.z * scale * w0.z, v0.w * scale * w0.w);
        p1.x = pack_bf2(v1.x * scale * w1.x, v1.y * scale * w1.y);
        p1.y = pack_bf2(v1.z * scale * w1.z, v1.w * scale * w1.w);
        *(uint2*)&op[lane * 4] = p0;
        *(uint2*)&op[256 + lane * 4] = p1;
        return;
    }
    const float* W; unsigned short* Wt; int K, N, n0, k0;
    if (b < 2048) {                                 // in_w: 64 x 16 tiles x 2
        int layer = b >> 10, idx = b & 1023;
        W  = in_w + (size_t)layer * 512 * 2048;
        Wt = in_wt_all + (size_t)layer * 2048 * 512;
        K = 512; N = 2048;
        n0 = (idx & 63) * 32; k0 = (idx >> 6) * 32;
    } else {                                        // out_w: 16 x 32 tiles x 2
        int bb = b - 2048;
        int layer = bb >> 9, idx = bb & 511;
        W  = out_w + (size_t)layer * 1024 * 512;
        Wt = out_wt_all + (size_t)layer * 512 * 1024;
        K = 1024; N = 512;
        n0 = (idx & 15) * 32; k0 = (idx >> 4) * 32;
    }
    __shared__ float tile[32][33];
    int tx = threadIdx.x & 31, ty = threadIdx.x >> 5;
    #pragma unroll
    for (int i = 0; i < 4; ++i)
        tile[ty + i*8][tx] = W[(size_t)(k0 + ty + i*8) * N + n0 + tx];
    __syncthreads();
    #pragma unroll
    for (int i = 0; i < 4; ++i)
        Wt[(size_t)(n0 + ty + i*8) * K + k0 + tx] = f2bf(tile[tx][ty + i*8]);
}

// -------- rmsnorm (bf16 out), layer >= 1 ------------------------------------
__global__ __launch_bounds__(64) void rmsnorm_bf_kernel(const float* __restrict__ x,
                                                        const float* __restrict__ w,
                                                        unsigned short* __restrict__ out) {
    int row = blockIdx.x;
    int tid = threadIdx.x;
    const float* xp = x + (size_t)row * D_MODEL;
    float4 v0 = *(const float4*)&xp[tid * 4];
    float4 v1 = *(const float4*)&xp[256 + tid * 4];
    float ss = v0.x*v0.x + v0.y*v0.y + v0.z*v0.z + v0.w*v0.w
             + v1.x*v1.x + v1.y*v1.y + v1.z*v1.z + v1.w*v1.w;
    #pragma unroll
    for (int off = 32; off > 0; off >>= 1) ss += __shfl_xor(ss, off);
    float scale = rsqrtf(ss * (1.f / D_MODEL) + 1e-5f);
    float4 w0 = *(const float4*)&w[tid * 4];
    float4 w1 = *(const float4*)&w[256 + tid * 4];
    unsigned short* op = out + (size_t)row * D_MODEL;
    uint2 p0, p1;
    p0.x = pack_bf2(v0.x * scale * w0.x, v0.y * scale * w0.y);
    p0.y = pack_bf2(v0.z * scale * w0.z, v0.w * scale * w0.w);
    p1.x = pack_bf2(v1.x * scale * w1.x, v1.y * scale * w1.y);
    p1.y = pack_bf2(v1.z * scale * w1.z, v1.w * scale * w1.w);
    *(uint2*)&op[tid * 4] = p0;
    *(uint2*)&op[256 + tid * 4] = p1;
}

// ===== templated bf16 MFMA GEMM =============================================
template<int BMT, int BNT, int EPI>
__global__ __launch_bounds__(256) void gemm_mfma_t(const unsigned short* __restrict__ A,
                                                   const unsigned short* __restrict__ Bt,
                                                   float* __restrict__ C,
                                                   unsigned short* __restrict__ Cb,
                                                   int K, int ldc) {
    constexpr int FM = BMT / 32;
    constexpr int FN = BNT / 32;
    __shared__ unsigned short As[BMT * 64];
    __shared__ unsigned short Bs[BNT * 64];
    int m0 = blockIdx.y * BMT;
    int n0 = blockIdx.x * BNT;
    int t = threadIdx.x;
    int lane = t & 63, wave = t >> 6;
    int wr = wave >> 1, wc = wave & 1;
    int srow = t >> 3;
    int sc8  = t & 7;
    f32x4 acc[FM][FN] = {};

    for (int k0 = 0; k0 < K; k0 += 64) {
        __syncthreads();
        #pragma unroll
        for (int i = 0; i < BMT / 32; ++i) {
            int row = i * 32 + srow;
            int csrc = sc8 ^ (row & 7);
            __builtin_amdgcn_global_load_lds(
                (const __attribute__((address_space(1))) void*)
                    &A[(size_t)(m0 + row) * K + k0 + csrc * 8],
                (__attribute__((address_space(3))) void*)
                    &As[row * 64 + sc8 * 8], 16, 0, 0);
        }
        #pragma unroll
        for (int i = 0; i < BNT / 32; ++i) {
            int row = i * 32 + srow;
            int csrc = sc8 ^ (row & 7);
            __builtin_amdgcn_global_load_lds(
                (const __attribute__((address_space(1))) void*)
                    &Bt[(size_t)(n0 + row) * K + k0 + csrc * 8],
                (__attribute__((address_space(3))) void*)
                    &Bs[row * 64 + sc8 * 8], 16, 0, 0);
        }
        __syncthreads();
        #pragma unroll
        for (int ks = 0; ks < 2; ++ks) {
            bf16x8 av[FM], bv[FN];
            #pragma unroll
            for (int f = 0; f < FM; ++f) {
                int ar = wr * (FM * 16) + f * 16 + (lane & 15);
                int ac = (ks * 4 + (lane >> 4)) ^ (ar & 7);
                av[f] = *reinterpret_cast<const bf16x8*>(&As[ar * 64 + ac * 8]);
            }
            #pragma unroll
            for (int f = 0; f < FN; ++f) {
                int br = wc * (FN * 16) + f * 16 + (lane & 15);
                int bc = (ks * 4 + (lane >> 4)) ^ (br & 7);
                bv[f] = *reinterpret_cast<const bf16x8*>(&Bs[br * 64 + bc * 8]);
            }
            #pragma unroll
            for (int fm = 0; fm < FM; ++fm)
                #pragma unroll
                for (int fn = 0; fn < FN; ++fn)
                    acc[fm][fn] = __builtin_amdgcn_mfma_f32_16x16x32_bf16(
                        av[fm], bv[fn], acc[fm][fn], 0, 0, 0);
        }
    }
    #pragma unroll
    for (int fm = 0; fm < FM; ++fm)
        #pragma unroll
        for (int fn = 0; fn < FN; ++fn) {
            int row = m0 + wr * (FM * 16) + fm * 16 + (lane >> 4) * 4;
            int col = n0 + wc * (FN * 16) + fn * 16 + (lane & 15);
            #pragma unroll
            for (int r = 0; r < 4; ++r) {
                if (EPI == 2) C[(size_t)(row + r) * ldc + col] += acc[fm][fn][r];
                else          Cb[(size_t)(row + r) * ldc + col] = f2bf(acc[fm][fn][r]);
            }
        }
}

// -------- conv+SiLU: u = silu(conv(xi)+cb), bf16 out ------------------------
__global__ void conv_bf_kernel(const unsigned short* __restrict__ xi,
                               const float* __restrict__ cw,
                               const float* __restrict__ cb,
                               unsigned short* __restrict__ u) {
    int g = blockIdx.x * blockDim.x + threadIdx.x;  // M*1024
    int d = g & (D_INNER - 1);
    int m = g >> 10;
    int l = m & (SEQ_L - 1);
    float4 w = *(const float4*)&cw[d * 4];
    const unsigned short* col = &xi[(size_t)m * 2048 + d];
    float x3 = bf2f(col[0]);
    float x2 = (l >= 1) ? bf2f(col[-2048]) : 0.f;
    float x1 = (l >= 2) ? bf2f(col[-4096]) : 0.f;
    float x0 = (l >= 3) ? bf2f(col[-6144]) : 0.f;
    u[g] = f2bf(silu_f(cb[d] + w.x*x0 + w.y*x1 + w.z*x2 + w.w*x3));
}

// -------- x_proj: xdbl[M,64] = u[M,1024] @ xp_w, f32 ------------------------
__global__ __launch_bounds__(256) void xproj_kernel(const unsigned short* __restrict__ u,
                                                    const float* __restrict__ Bw,
                                                    float* __restrict__ Cc) {
    __shared__ float Bsh[64][68];
    __shared__ float Ash[4][64];
    int row0 = blockIdx.x * 4;
    int t = threadIdx.x;
    int tr = t >> 6, c = t & 63;
    int kk = t >> 2, cb4 = (t & 3) << 4;
    float acc = 0.f;
    for (int k0 = 0; k0 < 1024; k0 += 64) {
        __syncthreads();
        #pragma unroll
        for (int j = 0; j < 4; ++j) {
            float4 v = *(const float4*)&Bw[(size_t)(k0 + kk) * 64 + cb4 + j * 4];
            *(float4*)&Bsh[kk][cb4 + j * 4] = v;
        }
        Ash[tr][c] = bf2f(u[(size_t)(row0 + tr) * 1024 + k0 + c]);
        __syncthreads();
        #pragma unroll
        for (int k = 0; k < 64; ++k)
            acc = fmaf(Ash[tr][k], Bsh[k][c], acc);
    }
    Cc[(size_t)(row0 + tr) * 64 + c] = acc;
}

// -------- dt_proj f32 GEMM (K=32) + softplus -> delta bf16 ------------------
#define BM 64
#define BN 64
#define BKK 16
__global__ __launch_bounds__(256) void gemm_dt(const float* __restrict__ A,
                                               const float* __restrict__ Bm,
                                               const float* __restrict__ bias,
                                               unsigned short* __restrict__ Cb,
                                               int lda, int ldb, int ldc) {
    __shared__ float As[BM][BKK + 4];
    __shared__ float Bs[BKK][BN];
    int tid = threadIdx.x;
    int n0 = blockIdx.x * BN;
    int m0 = blockIdx.y * BM;
    int tx4 = (tid & 15) << 2;
    int ty4 = (tid >> 4) << 2;
    int arow = tid >> 2, akk = (tid & 3) << 2;
    int brow = tid >> 4, bcol = (tid & 15) << 2;
    float acc[4][4] = {};
    for (int k0 = 0; k0 < 32; k0 += BKK) {
        float4 av = *(const float4*)&A[(size_t)(m0 + arow) * lda + k0 + akk];
        float4 bv = *(const float4*)&Bm[(size_t)(k0 + brow) * ldb + n0 + bcol];
        *(float4*)&As[arow][akk] = av;
        *(float4*)&Bs[brow][bcol] = bv;
        __syncthreads();
        #pragma unroll
        for (int k = 0; k < BKK; ++k) {
            float a0 = As[ty4 + 0][k];
            float a1 = As[ty4 + 1][k];
            float a2 = As[ty4 + 2][k];
            float a3 = As[ty4 + 3][k];
            float4 b = *(float4*)&Bs[k][tx4];
            acc[0][0] = fmaf(a0, b.x, acc[0][0]); acc[0][1] = fmaf(a0, b.y, acc[0][1]);
            acc[0][2] = fmaf(a0, b.z, acc[0][2]); acc[0][3] = fmaf(a0, b.w, acc[0][3]);
            acc[1][0] = fmaf(a1, b.x, acc[1][0]); acc[1][1] = fmaf(a1, b.y, acc[1][1]);
            acc[1][2] = fmaf(a1, b.z, acc[1][2]); acc[1][3] = fmaf(a1, b.w, acc[1][3]);
            acc[2][0] = fmaf(a2, b.x, acc[2][0]); acc[2][1] = fmaf(a2, b.y, acc[2][1]);
            acc[2][2] = fmaf(a2, b.z, acc[2][2]); acc[2][3] = fmaf(a2, b.w, acc[2][3]);
            acc[3][0] = fmaf(a3, b.x, acc[3][0]); acc[3][1] = fmaf(a3, b.y, acc[3][1]);
            acc[3][2] = fmaf(a3, b.z, acc[3][2]); acc[3][3] = fmaf(a3, b.w, acc[3][3]);
        }
        __syncthreads();
    }
    #pragma unroll
    for (int i = 0; i < 4; ++i) {
        int m = m0 + ty4 + i;
        float4 bb = *(const float4*)&bias[n0 + tx4];
        uint2 pv;
        pv.x = pack_bf2(softplus_f(acc[i][0] + bb.x), softplus_f(acc[i][1] + bb.y));
        pv.y = pack_bf2(softplus_f(acc[i][2] + bb.z), softplus_f(acc[i][3] + bb.w));
        *(uint2*)&Cb[(size_t)m * ldc + n0 + tx4] = pv;
    }
}

// ======================= chunk-parallel selective scan (NC=64) ==============
__global__ __launch_bounds__(256) void scan_p1i(const unsigned short* __restrict__ u,
                                                const unsigned short* __restrict__ delta,
                                                const float* __restrict__ xdbl,
                                                const float* __restrict__ A_log,
                                                float* __restrict__ aprod,
                                                float* __restrict__ hloc) {
    int tid = threadIdx.x;
    int d = blockIdx.x * 256 + tid;
    int b = blockIdx.y, c = blockIdx.z;
    int l0 = c * LC;
    __shared__ float sBC[LC][32];
    for (int i = tid; i < LC * 32; i += 256) {
        int l = i >> 5, j = i & 31;
        sBC[l][j] = xdbl[(size_t)(b * SEQ_L + l0 + l) * 64 + 32 + j];
    }
    __syncthreads();
    float A_[D_STATE], h[D_STATE], ap[D_STATE];
    #pragma unroll
    for (int n = 0; n < D_STATE; ++n) {
        A_[n] = -__expf(A_log[(size_t)d * D_STATE + n]);
        h[n] = 0.f; ap[n] = 1.f;
    }
    const unsigned short* ucol = u + (size_t)(b * SEQ_L + l0) * D_INNER + d;
    const unsigned short* dcol = delta + (size_t)(b * SEQ_L + l0) * D_INNER + d;
    for (int l = 0; l < LC; ++l) {
        float dtv = bf2f(dcol[l * D_INNER]);
        float uu = bf2f(ucol[l * D_INNER]);
        float du = dtv * uu;
        #pragma unroll
        for (int n = 0; n < D_STATE; ++n) {
            float e = __expf(dtv * A_[n]);
            h[n] = fmaf(e, h[n], du * sBC[l][n]);
            ap[n] *= e;
        }
    }
    #pragma unroll
    for (int n = 0; n < D_STATE; ++n) {
        size_t o = (((size_t)b * NC + c) * D_STATE + n) * D_INNER + d;
        aprod[o] = ap[n];
        hloc[o] = h[n];
    }
}

__global__ __launch_bounds__(256) void scan_p2(const float* __restrict__ aprod,
                                               float* __restrict__ hloc) {
    int d = blockIdx.x * 256 + threadIdx.x;
    int n = blockIdx.y;
    int b = blockIdx.z;
    float h = 0.f;
    #pragma unroll 4
    for (int c = 0; c < NC; ++c) {
        size_t o = (((size_t)b * NC + c) * D_STATE + n) * D_INNER + d;
        float ap = aprod[o];
        float lc = hloc[o];
        hloc[o] = h;
        h = fmaf(ap, h, lc);
    }
}

__global__ __launch_bounds__(256) void scan_p3i(const unsigned short* __restrict__ u,
                                                const unsigned short* __restrict__ delta,
                                                const float* __restrict__ xdbl,
                                                const float* __restrict__ A_log,
                                                const float* __restrict__ Dp,
                                                const float* __restrict__ hinit,
                                                const unsigned short* __restrict__ xi,
                                                unsigned short* __restrict__ y) {
    int tid = threadIdx.x;
    int d = blockIdx.x * 256 + tid;
    int b = blockIdx.y, c = blockIdx.z;
    int l0 = c * LC;
    __shared__ float sBC[LC][32];
    for (int i = tid; i < LC * 32; i += 256) {
        int l = i >> 5, j = i & 31;
        sBC[l][j] = xdbl[(size_t)(b * SEQ_L + l0 + l) * 64 + 32 + j];
    }
    __syncthreads();
    float A_[D_STATE], h[D_STATE];
    #pragma unroll
    for (int n = 0; n < D_STATE; ++n) {
        A_[n] = -__expf(A_log[(size_t)d * D_STATE + n]);
        size_t o = (((size_t)b * NC + c) * D_STATE + n) * D_INNER + d;
        h[n] = hinit[o];
    }
    float Dd = Dp[d];
    const unsigned short* ucol = u  + (size_t)(b * SEQ_L + l0) * D_INNER + d;
    const unsigned short* dcol = delta + (size_t)(b * SEQ_L + l0) * D_INNER + d;
    const unsigned short* rcol = xi + (size_t)(b * SEQ_L + l0) * 2048 + 1024 + d;
    for (int l = 0; l < LC; ++l) {
        float dtv = bf2f(dcol[l * D_INNER]);
        float uu = bf2f(ucol[l * D_INNER]);
        float du = dtv * uu;
        float yv = 0.f;
        #pragma unroll
        for (int n = 0; n < D_STATE; ++n) {
            float e = __expf(dtv * A_[n]);
            h[n] = fmaf(e, h[n], du * sBC[l][n]);
            yv = fmaf(h[n], sBC[l][16 + n], yv);
        }
        yv = fmaf(uu, Dd, yv);
        float res = bf2f(rcol[l * 2048]);
        y[(size_t)(b * SEQ_L + l0 + l) * D_INNER + d] = f2bf(yv * silu_f(res));
    }
}

// ============== fused final rmsnorm + mean-pool (chunked over L) ============
__global__ __launch_bounds__(256) void rms_pool1(const float* __restrict__ x,
                                                 float* __restrict__ partial) {
    int blk = blockIdx.x;
    int b = blk >> 5, c = blk & 31;
    int wave = threadIdx.x >> 6, lane = threadIdx.x & 63;
    int row0 = b * SEQ_L + c * 32 + wave * 8;
    float4 a0 = make_float4(0.f, 0.f, 0.f, 0.f);
    float4 a1 = make_float4(0.f, 0.f, 0.f, 0.f);
    for (int r = 0; r < 8; ++r) {
        const float* xp = x + (size_t)(row0 + r) * D_MODEL;
        float4 v0 = *(const float4*)&xp[lane * 4];
        float4 v1 = *(const float4*)&xp[256 + lane * 4];
        float ss = v0.x*v0.x + v0.y*v0.y + v0.z*v0.z + v0.w*v0.w
                 + v1.x*v1.x + v1.y*v1.y + v1.z*v1.z + v1.w*v1.w;
        #pragma unroll
        for (int off = 32; off > 0; off >>= 1) ss += __shfl_xor(ss, off);
        float s = rsqrtf(ss * (1.f / D_MODEL) + 1e-5f);
        a0.x = fmaf(v0.x, s, a0.x); a0.y = fmaf(v0.y, s, a0.y);
        a0.z = fmaf(v0.z, s, a0.z); a0.w = fmaf(v0.w, s, a0.w);
        a1.x = fmaf(v1.x, s, a1.x); a1.y = fmaf(v1.y, s, a1.y);
        a1.z = fmaf(v1.z, s, a1.z); a1.w = fmaf(v1.w, s, a1.w);
    }
    __shared__ float red[4][512];
    *(float4*)&red[wave][lane * 4] = a0;
    *(float4*)&red[wave][256 + lane * 4] = a1;
    __syncthreads();
    int d = threadIdx.x * 2;
    float s0 = red[0][d] + red[1][d] + red[2][d] + red[3][d];
    float s1 = red[0][d+1] + red[1][d+1] + red[2][d+1] + red[3][d+1];
    partial[(size_t)blk * 512 + d]     = s0;
    partial[(size_t)blk * 512 + d + 1] = s1;
}

// ---- tail2: pool-reduce + w-scale, emb projection + bias, logits (1 block) -
__global__ __launch_bounds__(512) void tail2_kernel(const float* __restrict__ ppart,
                                                    const float* __restrict__ w,
                                                    const float* __restrict__ pw,
                                                    const float* __restrict__ pb,
                                                    const float* __restrict__ cw,
                                                    const float* __restrict__ cb,
                                                    float* __restrict__ out) {
    __shared__ float sp[2][512];
    __shared__ float se[2][256];
    int t = threadIdx.x;
    {
        int b = t >> 8, dp = (t & 255) * 2;
        float s0 = 0.f, s1 = 0.f;
        #pragma unroll 8
        for (int c = 0; c < 32; ++c) {
            const float* pp = &ppart[((size_t)b * 32 + c) * 512 + dp];
            s0 += pp[0]; s1 += pp[1];
        }
        sp[b][dp]     = s0 * (1.f / SEQ_L) * w[dp];
        sp[b][dp + 1] = s1 * (1.f / SEQ_L) * w[dp + 1];
    }
    __syncthreads();
    {
        int b = t >> 8, e = t & 255;
        float acc = pb[e];
        #pragma unroll 8
        for (int k = 0; k < 512; ++k)
            acc = fmaf(sp[b][k], pw[(size_t)k * 256 + e], acc);
        out[14 + b * 256 + e] = acc;
        se[b][e] = acc;
    }
    __syncthreads();
    {
        int wave = t >> 6, lane = t & 63;
        for (int idx = wave; idx < 14; idx += 8) {
            int bb = idx / 7, cc = idx % 7;
            float a = 0.f;
            #pragma unroll
            for (int i = 0; i < 4; ++i) {
                int k = lane + i * 64;
                a = fmaf(se[bb][k], cw[k * 7 + cc], a);
            }
            #pragma unroll
            for (int off = 32; off > 0; off >>= 1) a += __shfl_xor(a, off);
            if (lane == 0) out[bb * 7 + cc] = a + cb[cc];
        }
    }
}

extern "C" void kernel_launch(void* const* d_in, const int* in_sizes, int n_in,
                              void* d_out, int out_size, void* d_ws, size_t ws_size,
                              hipStream_t stream) {
    const int*   ids    = (const int*)d_in[0];
    const float* emb    = (const float*)d_in[1];
    const float* norm_w = (const float*)d_in[2];
    const float* in_w   = (const float*)d_in[3];
    const float* conv_w = (const float*)d_in[4];
    const float* conv_b = (const float*)d_in[5];
    const float* xp_w   = (const float*)d_in[6];
    const float* dt_w   = (const float*)d_in[7];
    const float* dt_b   = (const float*)d_in[8];
    const float* A_log  = (const float*)d_in[9];
    const float* Dp     = (const float*)d_in[10];
    const float* out_w  = (const float*)d_in[11];
    const float* normf  = (const float*)d_in[12];
    const float* proj_w = (const float*)d_in[13];
    const float* proj_b = (const float*)d_in[14];
    const float* cls_w  = (const float*)d_in[15];
    const float* cls_b  = (const float*)d_in[16];
    float* out = (float*)d_out;

    float* p = (float*)d_ws;
    float* x      = p; p += 1 << 20;          // [2048][512] f32
    float* xnr    = p; p += 1 << 20;          // xn_bf / ppart
    float* xrr    = p; p += 2 << 20;          // xr_bf [2048][2048] bf16
    float* urr    = p; p += 1 << 20;          // u_bf  [2048][1024] bf16
    float* deltab = p; p += 1 << 20;          // delta [2048][1024] bf16
    float* xdbl   = p; p += 1 << 17;          // [2048][64] f32
    float* wreg   = p; p += 1572864;          // in_wt x2 + out_wt x2 (bf16)
    float* aprod  = p; p += 2 << 20;          // [2][64][16][1024] f32
    float* hloc   = p; p += 2 << 20;          // same shape
    float* ybr    = p; p += 1 << 20;          // yb_bf [2048][1024] bf16

    unsigned short* xn_bf  = (unsigned short*)xnr;
    float*          ppart  = xnr;
    unsigned short* xr_bf  = (unsigned short*)xrr;
    unsigned short* u_bf   = (unsigned short*)urr;
    unsigned short* dt_bf  = (unsigned short*)deltab;
    unsigned short* in_wt_all  = (unsigned short*)wreg;
    unsigned short* out_wt_all = (unsigned short*)(wreg + (1 << 20));
    unsigned short* yb_bf  = (unsigned short*)ybr;

    init_kernel<<<3584, 256, 0, stream>>>(
        ids, emb, norm_w, in_w, out_w, x, xn_bf, in_wt_all, out_wt_all);

    for (int i = 0; i < NLAYER; ++i) {
        unsigned short* in_wt  = in_wt_all  + (size_t)i * 2048 * 512;
        unsigned short* out_wt = out_wt_all + (size_t)i * 512 * 1024;
        const float* cwi  = conv_w + (size_t)i * D_INNER * 4;
        const float* cbi  = conv_b + (size_t)i * D_INNER;
        const float* dtwi = dt_w + (size_t)i * DT_RANK * D_INNER;
        const float* dtbi = dt_b + (size_t)i * D_INNER;
        const float* Ali  = A_log + (size_t)i * D_INNER * D_STATE;
        const float* Dpi  = Dp + (size_t)i * D_INNER;

        if (i > 0)
            rmsnorm_bf_kernel<<<M_ROWS, 64, 0, stream>>>(x, norm_w + i * D_MODEL, xn_bf);
        gemm_mfma_t<128, 64, 3><<<dim3(2048 / 64, M_ROWS / 128), 256, 0, stream>>>(
            xn_bf, in_wt, nullptr, xr_bf, 512, 2048);
        conv_bf_kernel<<<(M_ROWS * D_INNER) / 256, 256, 0, stream>>>(
            xr_bf, cwi, cbi, u_bf);
        xproj_kernel<<<M_ROWS / 4, 256, 0, stream>>>(
            u_bf, xp_w + (size_t)i * D_INNER * 64, xdbl);
        gemm_dt<<<dim3(1024 / BN, M_ROWS / BM), 256, 0, stream>>>(
            xdbl, dtwi, dtbi, dt_bf, 64, 1024, 1024);
        scan_p1i<<<dim3(4, BATCH, NC), 256, 0, stream>>>(
            u_bf, dt_bf, xdbl, Ali, aprod, hloc);
        scan_p2<<<dim3(4, D_STATE, BATCH), 256, 0, stream>>>(aprod, hloc);
        scan_p3i<<<dim3(4, BATCH, NC), 256, 0, stream>>>(
            u_bf, dt_bf, xdbl, Ali, Dpi, hloc, xr_bf, yb_bf);
        gemm_mfma_t<64, 32, 2><<<dim3(512 / 32, M_ROWS / 64), 256, 0, stream>>>(
            yb_bf, out_wt, x, nullptr, 1024, 512);
    }

    rms_pool1<<<BATCH * 32, 256, 0, stream>>>(x, ppart);
    tail2_kernel<<<1, 512, 0, stream>>>(ppart, normf, proj_w, proj_b, cls_w, cls_b, out);
}

// Round 19
// 221.344 us; speedup vs baseline: 1.1673x; 1.0737x over previous
//
#include <hip/hip_runtime.h>
#include <cstddef>

#define D_MODEL   512
#define D_INNER   1024
#define D_STATE   16
#define DT_RANK   32
#define SEQ_L     1024
#define BATCH     2
#define NLAYER    2
#define M_ROWS    (BATCH * SEQ_L)   // 2048
#define NC        64                // scan chunks (measured best)
#define LC        (SEQ_L / NC)      // 16 timesteps per chunk

typedef __bf16 bf16x8 __attribute__((ext_vector_type(8)));
typedef float  f32x4  __attribute__((ext_vector_type(4)));

__device__ __forceinline__ float softplus_f(float x) {
    return fmaxf(x, 0.f) + log1pf(expf(-fabsf(x)));
}
__device__ __forceinline__ float silu_f(float x) {
    return x / (1.f + __expf(-x));
}
__device__ __forceinline__ unsigned short f2bf(float f) {
    unsigned u = __float_as_uint(f);
    return (unsigned short)((u + 0x7fffu + ((u >> 16) & 1u)) >> 16);
}
__device__ __forceinline__ float bf2f(unsigned short v) {
    return __uint_as_float(((unsigned)v) << 16);
}
__device__ __forceinline__ unsigned pack_bf2(float lo, float hi) {
    return (unsigned)f2bf(lo) | ((unsigned)f2bf(hi) << 16);
}

// ==== init (flat 3584-block grid): castT in_w + castT out_w + embed+rms0 ====
__global__ __launch_bounds__(256) void init_kernel(const int* __restrict__ ids,
                                                   const float* __restrict__ emb,
                                                   const float* __restrict__ nw0,
                                                   const float* __restrict__ in_w,
                                                   const float* __restrict__ out_w,
                                                   float* __restrict__ x,
                                                   unsigned short* __restrict__ xn_bf,
                                                   unsigned short* __restrict__ in_wt_all,
                                                   unsigned short* __restrict__ out_wt_all) {
    int b = blockIdx.x;
    if (b >= 3072) {                                // embed + layer-0 rmsnorm
        int blk = b - 3072;                         // 0..511, 4 rows each
        int wave = threadIdx.x >> 6, lane = threadIdx.x & 63;
        int m = blk * 4 + wave;
        int row = ids[m];
        const float* ep = emb + (size_t)row * D_MODEL;
        float4 v0 = *(const float4*)&ep[lane * 4];
        float4 v1 = *(const float4*)&ep[256 + lane * 4];
        float* xp = x + (size_t)m * D_MODEL;
        *(float4*)&xp[lane * 4] = v0;
        *(float4*)&xp[256 + lane * 4] = v1;
        float ss = v0.x*v0.x + v0.y*v0.y + v0.z*v0.z + v0.w*v0.w
                 + v1.x*v1.x + v1.y*v1.y + v1.z*v1.z + v1.w*v1.w;
        #pragma unroll
        for (int off = 32; off > 0; off >>= 1) ss += __shfl_xor(ss, off);
        float scale = rsqrtf(ss * (1.f / D_MODEL) + 1e-5f);
        float4 w0 = *(const float4*)&nw0[lane * 4];
        float4 w1 = *(const float4*)&nw0[256 + lane * 4];
        unsigned short* op = xn_bf + (size_t)m * D_MODEL;
        uint2 p0, p1;
        p0.x = pack_bf2(v0.x * scale * w0.x, v0.y * scale * w0.y);
        p0.y = pack_bf2(v0.z * scale * w0.z, v0.w * scale * w0.w);
        p1.x = pack_bf2(v1.x * scale * w1.x, v1.y * scale * w1.y);
        p1.y = pack_bf2(v1.z * scale * w1.z, v1.w * scale * w1.w);
        *(uint2*)&op[lane * 4] = p0;
        *(uint2*)&op[256 + lane * 4] = p1;
        return;
    }
    const float* W; unsigned short* Wt; int K, N, n0, k0;
    if (b < 2048) {                                 // in_w: 64 x 16 tiles x 2
        int layer = b >> 10, idx = b & 1023;
        W  = in_w + (size_t)layer * 512 * 2048;
        Wt = in_wt_all + (size_t)layer * 2048 * 512;
        K = 512; N = 2048;
        n0 = (idx & 63) * 32; k0 = (idx >> 6) * 32;
    } else {                                        // out_w: 16 x 32 tiles x 2
        int bb = b - 2048;
        int layer = bb >> 9, idx = bb & 511;
        W  = out_w + (size_t)layer * 1024 * 512;
        Wt = out_wt_all + (size_t)layer * 512 * 1024;
        K = 1024; N = 512;
        n0 = (idx & 15) * 32; k0 = (idx >> 4) * 32;
    }
    __shared__ float tile[32][33];
    int tx = threadIdx.x & 31, ty = threadIdx.x >> 5;
    #pragma unroll
    for (int i = 0; i < 4; ++i)
        tile[ty + i*8][tx] = W[(size_t)(k0 + ty + i*8) * N + n0 + tx];
    __syncthreads();
    #pragma unroll
    for (int i = 0; i < 4; ++i)
        Wt[(size_t)(n0 + ty + i*8) * K + k0 + tx] = f2bf(tile[tx][ty + i*8]);
}

// -------- rmsnorm (bf16 out), layer >= 1 ------------------------------------
__global__ __launch_bounds__(64) void rmsnorm_bf_kernel(const float* __restrict__ x,
                                                        const float* __restrict__ w,
                                                        unsigned short* __restrict__ out) {
    int row = blockIdx.x;
    int tid = threadIdx.x;
    const float* xp = x + (size_t)row * D_MODEL;
    float4 v0 = *(const float4*)&xp[tid * 4];
    float4 v1 = *(const float4*)&xp[256 + tid * 4];
    float ss = v0.x*v0.x + v0.y*v0.y + v0.z*v0.z + v0.w*v0.w
             + v1.x*v1.x + v1.y*v1.y + v1.z*v1.z + v1.w*v1.w;
    #pragma unroll
    for (int off = 32; off > 0; off >>= 1) ss += __shfl_xor(ss, off);
    float scale = rsqrtf(ss * (1.f / D_MODEL) + 1e-5f);
    float4 w0 = *(const float4*)&w[tid * 4];
    float4 w1 = *(const float4*)&w[256 + tid * 4];
    unsigned short* op = out + (size_t)row * D_MODEL;
    uint2 p0, p1;
    p0.x = pack_bf2(v0.x * scale * w0.x, v0.y * scale * w0.y);
    p0.y = pack_bf2(v0.z * scale * w0.z, v0.w * scale * w0.w);
    p1.x = pack_bf2(v1.x * scale * w1.x, v1.y * scale * w1.y);
    p1.y = pack_bf2(v1.z * scale * w1.z, v1.w * scale * w1.w);
    *(uint2*)&op[tid * 4] = p0;
    *(uint2*)&op[256 + tid * 4] = p1;
}

// ===== templated bf16 MFMA GEMM =============================================
template<int BMT, int BNT, int EPI>
__global__ __launch_bounds__(256) void gemm_mfma_t(const unsigned short* __restrict__ A,
                                                   const unsigned short* __restrict__ Bt,
                                                   float* __restrict__ C,
                                                   unsigned short* __restrict__ Cb,
                                                   int K, int ldc) {
    constexpr int FM = BMT / 32;
    constexpr int FN = BNT / 32;
    __shared__ unsigned short As[BMT * 64];
    __shared__ unsigned short Bs[BNT * 64];
    int m0 = blockIdx.y * BMT;
    int n0 = blockIdx.x * BNT;
    int t = threadIdx.x;
    int lane = t & 63, wave = t >> 6;
    int wr = wave >> 1, wc = wave & 1;
    int srow = t >> 3;
    int sc8  = t & 7;
    f32x4 acc[FM][FN] = {};

    for (int k0 = 0; k0 < K; k0 += 64) {
        __syncthreads();
        #pragma unroll
        for (int i = 0; i < BMT / 32; ++i) {
            int row = i * 32 + srow;
            int csrc = sc8 ^ (row & 7);
            __builtin_amdgcn_global_load_lds(
                (const __attribute__((address_space(1))) void*)
                    &A[(size_t)(m0 + row) * K + k0 + csrc * 8],
                (__attribute__((address_space(3))) void*)
                    &As[row * 64 + sc8 * 8], 16, 0, 0);
        }
        #pragma unroll
        for (int i = 0; i < BNT / 32; ++i) {
            int row = i * 32 + srow;
            int csrc = sc8 ^ (row & 7);
            __builtin_amdgcn_global_load_lds(
                (const __attribute__((address_space(1))) void*)
                    &Bt[(size_t)(n0 + row) * K + k0 + csrc * 8],
                (__attribute__((address_space(3))) void*)
                    &Bs[row * 64 + sc8 * 8], 16, 0, 0);
        }
        __syncthreads();
        #pragma unroll
        for (int ks = 0; ks < 2; ++ks) {
            bf16x8 av[FM], bv[FN];
            #pragma unroll
            for (int f = 0; f < FM; ++f) {
                int ar = wr * (FM * 16) + f * 16 + (lane & 15);
                int ac = (ks * 4 + (lane >> 4)) ^ (ar & 7);
                av[f] = *reinterpret_cast<const bf16x8*>(&As[ar * 64 + ac * 8]);
            }
            #pragma unroll
            for (int f = 0; f < FN; ++f) {
                int br = wc * (FN * 16) + f * 16 + (lane & 15);
                int bc = (ks * 4 + (lane >> 4)) ^ (br & 7);
                bv[f] = *reinterpret_cast<const bf16x8*>(&Bs[br * 64 + bc * 8]);
            }
            #pragma unroll
            for (int fm = 0; fm < FM; ++fm)
                #pragma unroll
                for (int fn = 0; fn < FN; ++fn)
                    acc[fm][fn] = __builtin_amdgcn_mfma_f32_16x16x32_bf16(
                        av[fm], bv[fn], acc[fm][fn], 0, 0, 0);
        }
    }
    #pragma unroll
    for (int fm = 0; fm < FM; ++fm)
        #pragma unroll
        for (int fn = 0; fn < FN; ++fn) {
            int row = m0 + wr * (FM * 16) + fm * 16 + (lane >> 4) * 4;
            int col = n0 + wc * (FN * 16) + fn * 16 + (lane & 15);
            #pragma unroll
            for (int r = 0; r < 4; ++r) {
                if (EPI == 2) C[(size_t)(row + r) * ldc + col] += acc[fm][fn][r];
                else          Cb[(size_t)(row + r) * ldc + col] = f2bf(acc[fm][fn][r]);
            }
        }
}

// -------- conv+SiLU: u = silu(conv(xi)+cb), bf16 out ------------------------
__global__ void conv_bf_kernel(const unsigned short* __restrict__ xi,
                               const float* __restrict__ cw,
                               const float* __restrict__ cb,
                               unsigned short* __restrict__ u) {
    int g = blockIdx.x * blockDim.x + threadIdx.x;  // M*1024
    int d = g & (D_INNER - 1);
    int m = g >> 10;
    int l = m & (SEQ_L - 1);
    float4 w = *(const float4*)&cw[d * 4];
    const unsigned short* col = &xi[(size_t)m * 2048 + d];
    float x3 = bf2f(col[0]);
    float x2 = (l >= 1) ? bf2f(col[-2048]) : 0.f;
    float x1 = (l >= 2) ? bf2f(col[-4096]) : 0.f;
    float x0 = (l >= 3) ? bf2f(col[-6144]) : 0.f;
    u[g] = f2bf(silu_f(cb[d] + w.x*x0 + w.y*x1 + w.z*x2 + w.w*x3));
}

// -------- x_proj: xdbl[M,64] = u[M,1024] @ xp_w, f32 ------------------------
__global__ __launch_bounds__(256) void xproj_kernel(const unsigned short* __restrict__ u,
                                                    const float* __restrict__ Bw,
                                                    float* __restrict__ Cc) {
    __shared__ float Bsh[64][68];
    __shared__ float Ash[4][64];
    int row0 = blockIdx.x * 4;
    int t = threadIdx.x;
    int tr = t >> 6, c = t & 63;
    int kk = t >> 2, cb4 = (t & 3) << 4;
    float acc = 0.f;
    for (int k0 = 0; k0 < 1024; k0 += 64) {
        __syncthreads();
        #pragma unroll
        for (int j = 0; j < 4; ++j) {
            float4 v = *(const float4*)&Bw[(size_t)(k0 + kk) * 64 + cb4 + j * 4];
            *(float4*)&Bsh[kk][cb4 + j * 4] = v;
        }
        Ash[tr][c] = bf2f(u[(size_t)(row0 + tr) * 1024 + k0 + c]);
        __syncthreads();
        #pragma unroll
        for (int k = 0; k < 64; ++k)
            acc = fmaf(Ash[tr][k], Bsh[k][c], acc);
    }
    Cc[(size_t)(row0 + tr) * 64 + c] = acc;
}

// -------- dt_proj f32 GEMM (K=32) + softplus -> delta bf16 ------------------
#define BM 64
#define BN 64
#define BKK 16
__global__ __launch_bounds__(256) void gemm_dt(const float* __restrict__ A,
                                               const float* __restrict__ Bm,
                                               const float* __restrict__ bias,
                                               unsigned short* __restrict__ Cb,
                                               int lda, int ldb, int ldc) {
    __shared__ float As[BM][BKK + 4];
    __shared__ float Bs[BKK][BN];
    int tid = threadIdx.x;
    int n0 = blockIdx.x * BN;
    int m0 = blockIdx.y * BM;
    int tx4 = (tid & 15) << 2;
    int ty4 = (tid >> 4) << 2;
    int arow = tid >> 2, akk = (tid & 3) << 2;
    int brow = tid >> 4, bcol = (tid & 15) << 2;
    float acc[4][4] = {};
    for (int k0 = 0; k0 < 32; k0 += BKK) {
        float4 av = *(const float4*)&A[(size_t)(m0 + arow) * lda + k0 + akk];
        float4 bv = *(const float4*)&Bm[(size_t)(k0 + brow) * ldb + n0 + bcol];
        *(float4*)&As[arow][akk] = av;
        *(float4*)&Bs[brow][bcol] = bv;
        __syncthreads();
        #pragma unroll
        for (int k = 0; k < BKK; ++k) {
            float a0 = As[ty4 + 0][k];
            float a1 = As[ty4 + 1][k];
            float a2 = As[ty4 + 2][k];
            float a3 = As[ty4 + 3][k];
            float4 b = *(float4*)&Bs[k][tx4];
            acc[0][0] = fmaf(a0, b.x, acc[0][0]); acc[0][1] = fmaf(a0, b.y, acc[0][1]);
            acc[0][2] = fmaf(a0, b.z, acc[0][2]); acc[0][3] = fmaf(a0, b.w, acc[0][3]);
            acc[1][0] = fmaf(a1, b.x, acc[1][0]); acc[1][1] = fmaf(a1, b.y, acc[1][1]);
            acc[1][2] = fmaf(a1, b.z, acc[1][2]); acc[1][3] = fmaf(a1, b.w, acc[1][3]);
            acc[2][0] = fmaf(a2, b.x, acc[2][0]); acc[2][1] = fmaf(a2, b.y, acc[2][1]);
            acc[2][2] = fmaf(a2, b.z, acc[2][2]); acc[2][3] = fmaf(a2, b.w, acc[2][3]);
            acc[3][0] = fmaf(a3, b.x, acc[3][0]); acc[3][1] = fmaf(a3, b.y, acc[3][1]);
            acc[3][2] = fmaf(a3, b.z, acc[3][2]); acc[3][3] = fmaf(a3, b.w, acc[3][3]);
        }
        __syncthreads();
    }
    #pragma unroll
    for (int i = 0; i < 4; ++i) {
        int m = m0 + ty4 + i;
        float4 bb = *(const float4*)&bias[n0 + tx4];
        uint2 pv;
        pv.x = pack_bf2(softplus_f(acc[i][0] + bb.x), softplus_f(acc[i][1] + bb.y));
        pv.y = pack_bf2(softplus_f(acc[i][2] + bb.z), softplus_f(acc[i][3] + bb.w));
        *(uint2*)&Cb[(size_t)m * ldc + n0 + tx4] = pv;
    }
}

// ======================= chunk-parallel selective scan (NC=64) ==============
__global__ __launch_bounds__(256) void scan_p1i(const unsigned short* __restrict__ u,
                                                const unsigned short* __restrict__ delta,
                                                const float* __restrict__ xdbl,
                                                const float* __restrict__ A_log,
                                                float* __restrict__ aprod,
                                                float* __restrict__ hloc) {
    int tid = threadIdx.x;
    int d = blockIdx.x * 256 + tid;
    int b = blockIdx.y, c = blockIdx.z;
    int l0 = c * LC;
    __shared__ float sBC[LC][32];
    for (int i = tid; i < LC * 32; i += 256) {
        int l = i >> 5, j = i & 31;
        sBC[l][j] = xdbl[(size_t)(b * SEQ_L + l0 + l) * 64 + 32 + j];
    }
    __syncthreads();
    float A_[D_STATE], h[D_STATE], ap[D_STATE];
    #pragma unroll
    for (int n = 0; n < D_STATE; ++n) {
        A_[n] = -__expf(A_log[(size_t)d * D_STATE + n]);
        h[n] = 0.f; ap[n] = 1.f;
    }
    const unsigned short* ucol = u + (size_t)(b * SEQ_L + l0) * D_INNER + d;
    const unsigned short* dcol = delta + (size_t)(b * SEQ_L + l0) * D_INNER + d;
    for (int l = 0; l < LC; ++l) {
        float dtv = bf2f(dcol[l * D_INNER]);
        float uu = bf2f(ucol[l * D_INNER]);
        float du = dtv * uu;
        #pragma unroll
        for (int n = 0; n < D_STATE; ++n) {
            float e = __expf(dtv * A_[n]);
            h[n] = fmaf(e, h[n], du * sBC[l][n]);
            ap[n] *= e;
        }
    }
    #pragma unroll
    for (int n = 0; n < D_STATE; ++n) {
        size_t o = (((size_t)b * NC + c) * D_STATE + n) * D_INNER + d;
        aprod[o] = ap[n];
        hloc[o] = h[n];
    }
}

__global__ __launch_bounds__(256) void scan_p2(const float* __restrict__ aprod,
                                               float* __restrict__ hloc) {
    int d = blockIdx.x * 256 + threadIdx.x;
    int n = blockIdx.y;
    int b = blockIdx.z;
    float h = 0.f;
    #pragma unroll 4
    for (int c = 0; c < NC; ++c) {
        size_t o = (((size_t)b * NC + c) * D_STATE + n) * D_INNER + d;
        float ap = aprod[o];
        float lc = hloc[o];
        hloc[o] = h;
        h = fmaf(ap, h, lc);
    }
}

__global__ __launch_bounds__(256) void scan_p3i(const unsigned short* __restrict__ u,
                                                const unsigned short* __restrict__ delta,
                                                const float* __restrict__ xdbl,
                                                const float* __restrict__ A_log,
                                                const float* __restrict__ Dp,
                                                const float* __restrict__ hinit,
                                                const unsigned short* __restrict__ xi,
                                                unsigned short* __restrict__ y) {
    int tid = threadIdx.x;
    int d = blockIdx.x * 256 + tid;
    int b = blockIdx.y, c = blockIdx.z;
    int l0 = c * LC;
    __shared__ float sBC[LC][32];
    for (int i = tid; i < LC * 32; i += 256) {
        int l = i >> 5, j = i & 31;
        sBC[l][j] = xdbl[(size_t)(b * SEQ_L + l0 + l) * 64 + 32 + j];
    }
    __syncthreads();
    float A_[D_STATE], h[D_STATE];
    #pragma unroll
    for (int n = 0; n < D_STATE; ++n) {
        A_[n] = -__expf(A_log[(size_t)d * D_STATE + n]);
        size_t o = (((size_t)b * NC + c) * D_STATE + n) * D_INNER + d;
        h[n] = hinit[o];
    }
    float Dd = Dp[d];
    const unsigned short* ucol = u  + (size_t)(b * SEQ_L + l0) * D_INNER + d;
    const unsigned short* dcol = delta + (size_t)(b * SEQ_L + l0) * D_INNER + d;
    const unsigned short* rcol = xi + (size_t)(b * SEQ_L + l0) * 2048 + 1024 + d;
    for (int l = 0; l < LC; ++l) {
        float dtv = bf2f(dcol[l * D_INNER]);
        float uu = bf2f(ucol[l * D_INNER]);
        float du = dtv * uu;
        float yv = 0.f;
        #pragma unroll
        for (int n = 0; n < D_STATE; ++n) {
            float e = __expf(dtv * A_[n]);
            h[n] = fmaf(e, h[n], du * sBC[l][n]);
            yv = fmaf(h[n], sBC[l][16 + n], yv);
        }
        yv = fmaf(uu, Dd, yv);
        float res = bf2f(rcol[l * 2048]);
        y[(size_t)(b * SEQ_L + l0 + l) * D_INNER + d] = f2bf(yv * silu_f(res));
    }
}

// ============== fused final rmsnorm + mean-pool (chunked over L) ============
__global__ __launch_bounds__(256) void rms_pool1(const float* __restrict__ x,
                                                 float* __restrict__ partial) {
    int blk = blockIdx.x;
    int b = blk >> 5, c = blk & 31;
    int wave = threadIdx.x >> 6, lane = threadIdx.x & 63;
    int row0 = b * SEQ_L + c * 32 + wave * 8;
    float4 a0 = make_float4(0.f, 0.f, 0.f, 0.f);
    float4 a1 = make_float4(0.f, 0.f, 0.f, 0.f);
    for (int r = 0; r < 8; ++r) {
        const float* xp = x + (size_t)(row0 + r) * D_MODEL;
        float4 v0 = *(const float4*)&xp[lane * 4];
        float4 v1 = *(const float4*)&xp[256 + lane * 4];
        float ss = v0.x*v0.x + v0.y*v0.y + v0.z*v0.z + v0.w*v0.w
                 + v1.x*v1.x + v1.y*v1.y + v1.z*v1.z + v1.w*v1.w;
        #pragma unroll
        for (int off = 32; off > 0; off >>= 1) ss += __shfl_xor(ss, off);
        float s = rsqrtf(ss * (1.f / D_MODEL) + 1e-5f);
        a0.x = fmaf(v0.x, s, a0.x); a0.y = fmaf(v0.y, s, a0.y);
        a0.z = fmaf(v0.z, s, a0.z); a0.w = fmaf(v0.w, s, a0.w);
        a1.x = fmaf(v1.x, s, a1.x); a1.y = fmaf(v1.y, s, a1.y);
        a1.z = fmaf(v1.z, s, a1.z); a1.w = fmaf(v1.w, s, a1.w);
    }
    __shared__ float red[4][512];
    *(float4*)&red[wave][lane * 4] = a0;
    *(float4*)&red[wave][256 + lane * 4] = a1;
    __syncthreads();
    int d = threadIdx.x * 2;
    float s0 = red[0][d] + red[1][d] + red[2][d] + red[3][d];
    float s1 = red[0][d+1] + red[1][d+1] + red[2][d+1] + red[3][d+1];
    partial[(size_t)blk * 512 + d]     = s0;
    partial[(size_t)blk * 512 + d + 1] = s1;
}

// ---- emb_proj k-split: 16 blocks read proj_w in parallel -------------------
__global__ __launch_bounds__(256) void embp1f(const float* __restrict__ ppart,
                                              const float* __restrict__ w,
                                              const float* __restrict__ pw,
                                              float* __restrict__ partial) {
    int b = blockIdx.x, kc = blockIdx.y;
    int t = threadIdx.x;
    __shared__ float sp[64];
    if (t < 64) {
        int dd = kc * 64 + t;
        float s = 0.f;
        #pragma unroll
        for (int c = 0; c < 32; ++c)
            s += ppart[((size_t)b * 32 + c) * 512 + dd];
        sp[t] = s * (1.f / SEQ_L) * w[dd];
    }
    __syncthreads();
    float acc = 0.f;
    #pragma unroll 8
    for (int i = 0; i < 64; ++i) {
        int k = kc * 64 + i;
        acc = fmaf(sp[i], pw[(size_t)k * 256 + t], acc);
    }
    partial[((size_t)b * 8 + kc) * 256 + t] = acc;
}

// ---- head: partial-reduce + bias -> emotion_emb, then logits (1 block) -----
__global__ __launch_bounds__(512) void head_kernel(const float* __restrict__ eparts,
                                                   const float* __restrict__ pb,
                                                   const float* __restrict__ cw,
                                                   const float* __restrict__ cb,
                                                   float* __restrict__ out) {
    __shared__ float se[2][256];
    int t = threadIdx.x;
    int b = t >> 8, e = t & 255;
    float s = pb[e];
    #pragma unroll
    for (int kc = 0; kc < 8; ++kc)
        s += eparts[((size_t)b * 8 + kc) * 256 + e];
    out[14 + b * 256 + e] = s;
    se[b][e] = s;
    __syncthreads();
    int wave = t >> 6, lane = t & 63;
    for (int idx = wave; idx < 14; idx += 8) {
        int bb = idx / 7, cc = idx % 7;
        float a = 0.f;
        #pragma unroll
        for (int i = 0; i < 4; ++i) {
            int k = lane + i * 64;
            a = fmaf(se[bb][k], cw[k * 7 + cc], a);
        }
        #pragma unroll
        for (int off = 32; off > 0; off >>= 1) a += __shfl_xor(a, off);
        if (lane == 0) out[bb * 7 + cc] = a + cb[cc];
    }
}

extern "C" void kernel_launch(void* const* d_in, const int* in_sizes, int n_in,
                              void* d_out, int out_size, void* d_ws, size_t ws_size,
                              hipStream_t stream) {
    const int*   ids    = (const int*)d_in[0];
    const float* emb    = (const float*)d_in[1];
    const float* norm_w = (const float*)d_in[2];
    const float* in_w   = (const float*)d_in[3];
    const float* conv_w = (const float*)d_in[4];
    const float* conv_b = (const float*)d_in[5];
    const float* xp_w   = (const float*)d_in[6];
    const float* dt_w   = (const float*)d_in[7];
    const float* dt_b   = (const float*)d_in[8];
    const float* A_log  = (const float*)d_in[9];
    const float* Dp     = (const float*)d_in[10];
    const float* out_w  = (const float*)d_in[11];
    const float* normf  = (const float*)d_in[12];
    const float* proj_w = (const float*)d_in[13];
    const float* proj_b = (const float*)d_in[14];
    const float* cls_w  = (const float*)d_in[15];
    const float* cls_b  = (const float*)d_in[16];
    float* out = (float*)d_out;

    float* p = (float*)d_ws;
    float* x      = p; p += 1 << 20;          // [2048][512] f32
    float* xnr    = p; p += 1 << 20;          // xn_bf / ppart
    float* xrr    = p; p += 2 << 20;          // xr_bf [2048][2048] bf16
    float* urr    = p; p += 1 << 20;          // u_bf  [2048][1024] bf16
    float* deltab = p; p += 1 << 20;          // delta [2048][1024] bf16
    float* xdbl   = p; p += 1 << 17;          // [2048][64] f32
    float* wreg   = p; p += 1572864;          // in_wt x2 + out_wt x2 (bf16)
    float* aprod  = p; p += 2 << 20;          // [2][64][16][1024] f32
    float* hloc   = p; p += 2 << 20;          // same shape
    float* ybr    = p; p += 1 << 20;          // yb_bf [2048][1024] bf16
    float* eparts = p; p += 4096;             // [2][8][256] f32

    unsigned short* xn_bf  = (unsigned short*)xnr;
    float*          ppart  = xnr;
    unsigned short* xr_bf  = (unsigned short*)xrr;
    unsigned short* u_bf   = (unsigned short*)urr;
    unsigned short* dt_bf  = (unsigned short*)deltab;
    unsigned short* in_wt_all  = (unsigned short*)wreg;
    unsigned short* out_wt_all = (unsigned short*)(wreg + (1 << 20));
    unsigned short* yb_bf  = (unsigned short*)ybr;

    init_kernel<<<3584, 256, 0, stream>>>(
        ids, emb, norm_w, in_w, out_w, x, xn_bf, in_wt_all, out_wt_all);

    for (int i = 0; i < NLAYER; ++i) {
        unsigned short* in_wt  = in_wt_all  + (size_t)i * 2048 * 512;
        unsigned short* out_wt = out_wt_all + (size_t)i * 512 * 1024;
        const float* cwi  = conv_w + (size_t)i * D_INNER * 4;
        const float* cbi  = conv_b + (size_t)i * D_INNER;
        const float* dtwi = dt_w + (size_t)i * DT_RANK * D_INNER;
        const float* dtbi = dt_b + (size_t)i * D_INNER;
        const float* Ali  = A_log + (size_t)i * D_INNER * D_STATE;
        const float* Dpi  = Dp + (size_t)i * D_INNER;

        if (i > 0)
            rmsnorm_bf_kernel<<<M_ROWS, 64, 0, stream>>>(x, norm_w + i * D_MODEL, xn_bf);
        gemm_mfma_t<128, 64, 3><<<dim3(2048 / 64, M_ROWS / 128), 256, 0, stream>>>(
            xn_bf, in_wt, nullptr, xr_bf, 512, 2048);
        conv_bf_kernel<<<(M_ROWS * D_INNER) / 256, 256, 0, stream>>>(
            xr_bf, cwi, cbi, u_bf);
        xproj_kernel<<<M_ROWS / 4, 256, 0, stream>>>(
            u_bf, xp_w + (size_t)i * D_INNER * 64, xdbl);
        gemm_dt<<<dim3(1024 / BN, M_ROWS / BM), 256, 0, stream>>>(
            xdbl, dtwi, dtbi, dt_bf, 64, 1024, 1024);
        scan_p1i<<<dim3(4, BATCH, NC), 256, 0, stream>>>(
            u_bf, dt_bf, xdbl, Ali, aprod, hloc);
        scan_p2<<<dim3(4, D_STATE, BATCH), 256, 0, stream>>>(aprod, hloc);
        scan_p3i<<<dim3(4, BATCH, NC), 256, 0, stream>>>(
            u_bf, dt_bf, xdbl, Ali, Dpi, hloc, xr_bf, yb_bf);
        gemm_mfma_t<64, 32, 2><<<dim3(512 / 32, M_ROWS / 64), 256, 0, stream>>>(
            yb_bf, out_wt, x, nullptr, 1024, 512);
    }

    rms_pool1<<<BATCH * 32, 256, 0, stream>>>(x, ppart);
    embp1f<<<dim3(BATCH, 8), 256, 0, stream>>>(ppart, normf, proj_w, eparts);
    head_kernel<<<1, 512, 0, stream>>>(eparts, proj_b, cls_w, cls_b, out);
}

// Round 21
// 212.933 us; speedup vs baseline: 1.2134x; 1.0395x over previous
//
#include <hip/hip_runtime.h>
#include <cstddef>

#define D_MODEL   512
#define D_INNER   1024
#define D_STATE   16
#define DT_RANK   32
#define SEQ_L     1024
#define BATCH     2
#define NLAYER    2
#define M_ROWS    (BATCH * SEQ_L)   // 2048
#define NC        64                // scan chunks (measured best)
#define LC        (SEQ_L / NC)      // 16 timesteps per chunk

typedef __bf16 bf16x8 __attribute__((ext_vector_type(8)));
typedef float  f32x4  __attribute__((ext_vector_type(4)));

__device__ __forceinline__ float softplus_f(float x) {
    return fmaxf(x, 0.f) + log1pf(expf(-fabsf(x)));
}
__device__ __forceinline__ float silu_f(float x) {
    return x / (1.f + __expf(-x));
}
__device__ __forceinline__ unsigned short f2bf(float f) {
    unsigned u = __float_as_uint(f);
    return (unsigned short)((u + 0x7fffu + ((u >> 16) & 1u)) >> 16);
}
__device__ __forceinline__ float bf2f(unsigned short v) {
    return __uint_as_float(((unsigned)v) << 16);
}
__device__ __forceinline__ unsigned pack_bf2(float lo, float hi) {
    return (unsigned)f2bf(lo) | ((unsigned)f2bf(hi) << 16);
}

// ==== init (flat 3584-block grid): castT in_w + castT out_w + embed+rms0 ====
__global__ __launch_bounds__(256) void init_kernel(const int* __restrict__ ids,
                                                   const float* __restrict__ emb,
                                                   const float* __restrict__ nw0,
                                                   const float* __restrict__ in_w,
                                                   const float* __restrict__ out_w,
                                                   float* __restrict__ x,
                                                   unsigned short* __restrict__ xn_bf,
                                                   unsigned short* __restrict__ in_wt_all,
                                                   unsigned short* __restrict__ out_wt_all) {
    int b = blockIdx.x;
    if (b >= 3072) {                                // embed + layer-0 rmsnorm
        int blk = b - 3072;                         // 0..511, 4 rows each
        int wave = threadIdx.x >> 6, lane = threadIdx.x & 63;
        int m = blk * 4 + wave;
        int row = ids[m];
        const float* ep = emb + (size_t)row * D_MODEL;
        float4 v0 = *(const float4*)&ep[lane * 4];
        float4 v1 = *(const float4*)&ep[256 + lane * 4];
        float* xp = x + (size_t)m * D_MODEL;
        *(float4*)&xp[lane * 4] = v0;
        *(float4*)&xp[256 + lane * 4] = v1;
        float ss = v0.x*v0.x + v0.y*v0.y + v0.z*v0.z + v0.w*v0.w
                 + v1.x*v1.x + v1.y*v1.y + v1.z*v1.z + v1.w*v1.w;
        #pragma unroll
        for (int off = 32; off > 0; off >>= 1) ss += __shfl_xor(ss, off);
        float scale = rsqrtf(ss * (1.f / D_MODEL) + 1e-5f);
        float4 w0 = *(const float4*)&nw0[lane * 4];
        float4 w1 = *(const float4*)&nw0[256 + lane * 4];
        unsigned short* op = xn_bf + (size_t)m * D_MODEL;
        uint2 p0, p1;
        p0.x = pack_bf2(v0.x * scale * w0.x, v0.y * scale * w0.y);
        p0.y = pack_bf2(v0.z * scale * w0.z, v0.w * scale * w0.w);
        p1.x = pack_bf2(v1.x * scale * w1.x, v1.y * scale * w1.y);
        p1.y = pack_bf2(v1.z * scale * w1.z, v1.w * scale * w1.w);
        *(uint2*)&op[lane * 4] = p0;
        *(uint2*)&op[256 + lane * 4] = p1;
        return;
    }
    const float* W; unsigned short* Wt; int K, N, n0, k0;
    if (b < 2048) {                                 // in_w: 64 x 16 tiles x 2
        int layer = b >> 10, idx = b & 1023;
        W  = in_w + (size_t)layer * 512 * 2048;
        Wt = in_wt_all + (size_t)layer * 2048 * 512;
        K = 512; N = 2048;
        n0 = (idx & 63) * 32; k0 = (idx >> 6) * 32;
    } else {                                        // out_w: 16 x 32 tiles x 2
        int bb = b - 2048;
        int layer = bb >> 9, idx = bb & 511;
        W  = out_w + (size_t)layer * 1024 * 512;
        Wt = out_wt_all + (size_t)layer * 512 * 1024;
        K = 1024; N = 512;
        n0 = (idx & 15) * 32; k0 = (idx >> 4) * 32;
    }
    __shared__ float tile[32][33];
    int tx = threadIdx.x & 31, ty = threadIdx.x >> 5;
    #pragma unroll
    for (int i = 0; i < 4; ++i)
        tile[ty + i*8][tx] = W[(size_t)(k0 + ty + i*8) * N + n0 + tx];
    __syncthreads();
    #pragma unroll
    for (int i = 0; i < 4; ++i)
        Wt[(size_t)(n0 + ty + i*8) * K + k0 + tx] = f2bf(tile[tx][ty + i*8]);
}

// -------- rmsnorm (bf16 out), layer >= 1 ------------------------------------
__global__ __launch_bounds__(64) void rmsnorm_bf_kernel(const float* __restrict__ x,
                                                        const float* __restrict__ w,
                                                        unsigned short* __restrict__ out) {
    int row = blockIdx.x;
    int tid = threadIdx.x;
    const float* xp = x + (size_t)row * D_MODEL;
    float4 v0 = *(const float4*)&xp[tid * 4];
    float4 v1 = *(const float4*)&xp[256 + tid * 4];
    float ss = v0.x*v0.x + v0.y*v0.y + v0.z*v0.z + v0.w*v0.w
             + v1.x*v1.x + v1.y*v1.y + v1.z*v1.z + v1.w*v1.w;
    #pragma unroll
    for (int off = 32; off > 0; off >>= 1) ss += __shfl_xor(ss, off);
    float scale = rsqrtf(ss * (1.f / D_MODEL) + 1e-5f);
    float4 w0 = *(const float4*)&w[tid * 4];
    float4 w1 = *(const float4*)&w[256 + tid * 4];
    unsigned short* op = out + (size_t)row * D_MODEL;
    uint2 p0, p1;
    p0.x = pack_bf2(v0.x * scale * w0.x, v0.y * scale * w0.y);
    p0.y = pack_bf2(v0.z * scale * w0.z, v0.w * scale * w0.w);
    p1.x = pack_bf2(v1.x * scale * w1.x, v1.y * scale * w1.y);
    p1.y = pack_bf2(v1.z * scale * w1.z, v1.w * scale * w1.w);
    *(uint2*)&op[tid * 4] = p0;
    *(uint2*)&op[256 + tid * 4] = p1;
}

// ===== templated bf16 MFMA GEMM =============================================
template<int BMT, int BNT, int EPI>
__global__ __launch_bounds__(256) void gemm_mfma_t(const unsigned short* __restrict__ A,
                                                   const unsigned short* __restrict__ Bt,
                                                   float* __restrict__ C,
                                                   unsigned short* __restrict__ Cb,
                                                   int K, int ldc) {
    constexpr int FM = BMT / 32;
    constexpr int FN = BNT / 32;
    __shared__ unsigned short As[BMT * 64];
    __shared__ unsigned short Bs[BNT * 64];
    int m0 = blockIdx.y * BMT;
    int n0 = blockIdx.x * BNT;
    int t = threadIdx.x;
    int lane = t & 63, wave = t >> 6;
    int wr = wave >> 1, wc = wave & 1;
    int srow = t >> 3;
    int sc8  = t & 7;
    f32x4 acc[FM][FN] = {};

    for (int k0 = 0; k0 < K; k0 += 64) {
        __syncthreads();
        #pragma unroll
        for (int i = 0; i < BMT / 32; ++i) {
            int row = i * 32 + srow;
            int csrc = sc8 ^ (row & 7);
            __builtin_amdgcn_global_load_lds(
                (const __attribute__((address_space(1))) void*)
                    &A[(size_t)(m0 + row) * K + k0 + csrc * 8],
                (__attribute__((address_space(3))) void*)
                    &As[row * 64 + sc8 * 8], 16, 0, 0);
        }
        #pragma unroll
        for (int i = 0; i < BNT / 32; ++i) {
            int row = i * 32 + srow;
            int csrc = sc8 ^ (row & 7);
            __builtin_amdgcn_global_load_lds(
                (const __attribute__((address_space(1))) void*)
                    &Bt[(size_t)(n0 + row) * K + k0 + csrc * 8],
                (__attribute__((address_space(3))) void*)
                    &Bs[row * 64 + sc8 * 8], 16, 0, 0);
        }
        __syncthreads();
        #pragma unroll
        for (int ks = 0; ks < 2; ++ks) {
            bf16x8 av[FM], bv[FN];
            #pragma unroll
            for (int f = 0; f < FM; ++f) {
                int ar = wr * (FM * 16) + f * 16 + (lane & 15);
                int ac = (ks * 4 + (lane >> 4)) ^ (ar & 7);
                av[f] = *reinterpret_cast<const bf16x8*>(&As[ar * 64 + ac * 8]);
            }
            #pragma unroll
            for (int f = 0; f < FN; ++f) {
                int br = wc * (FN * 16) + f * 16 + (lane & 15);
                int bc = (ks * 4 + (lane >> 4)) ^ (br & 7);
                bv[f] = *reinterpret_cast<const bf16x8*>(&Bs[br * 64 + bc * 8]);
            }
            #pragma unroll
            for (int fm = 0; fm < FM; ++fm)
                #pragma unroll
                for (int fn = 0; fn < FN; ++fn)
                    acc[fm][fn] = __builtin_amdgcn_mfma_f32_16x16x32_bf16(
                        av[fm], bv[fn], acc[fm][fn], 0, 0, 0);
        }
    }
    #pragma unroll
    for (int fm = 0; fm < FM; ++fm)
        #pragma unroll
        for (int fn = 0; fn < FN; ++fn) {
            int row = m0 + wr * (FM * 16) + fm * 16 + (lane >> 4) * 4;
            int col = n0 + wc * (FN * 16) + fn * 16 + (lane & 15);
            #pragma unroll
            for (int r = 0; r < 4; ++r) {
                if (EPI == 2) C[(size_t)(row + r) * ldc + col] += acc[fm][fn][r];
                else          Cb[(size_t)(row + r) * ldc + col] = f2bf(acc[fm][fn][r]);
            }
        }
}

// -------- conv+SiLU: u = silu(conv(xi)+cb), bf16 out ------------------------
__global__ void conv_bf_kernel(const unsigned short* __restrict__ xi,
                               const float* __restrict__ cw,
                               const float* __restrict__ cb,
                               unsigned short* __restrict__ u) {
    int g = blockIdx.x * blockDim.x + threadIdx.x;  // M*1024
    int d = g & (D_INNER - 1);
    int m = g >> 10;
    int l = m & (SEQ_L - 1);
    float4 w = *(const float4*)&cw[d * 4];
    const unsigned short* col = &xi[(size_t)m * 2048 + d];
    float x3 = bf2f(col[0]);
    float x2 = (l >= 1) ? bf2f(col[-2048]) : 0.f;
    float x1 = (l >= 2) ? bf2f(col[-4096]) : 0.f;
    float x0 = (l >= 3) ? bf2f(col[-6144]) : 0.f;
    u[g] = f2bf(silu_f(cb[d] + w.x*x0 + w.y*x1 + w.z*x2 + w.w*x3));
}

// -------- x_proj: xdbl[M,64] = u[M,1024] @ xp_w, f32 ------------------------
__global__ __launch_bounds__(256) void xproj_kernel(const unsigned short* __restrict__ u,
                                                    const float* __restrict__ Bw,
                                                    float* __restrict__ Cc) {
    __shared__ float Bsh[64][68];
    __shared__ float Ash[4][64];
    int row0 = blockIdx.x * 4;
    int t = threadIdx.x;
    int tr = t >> 6, c = t & 63;
    int kk = t >> 2, cb4 = (t & 3) << 4;
    float acc = 0.f;
    for (int k0 = 0; k0 < 1024; k0 += 64) {
        __syncthreads();
        #pragma unroll
        for (int j = 0; j < 4; ++j) {
            float4 v = *(const float4*)&Bw[(size_t)(k0 + kk) * 64 + cb4 + j * 4];
            *(float4*)&Bsh[kk][cb4 + j * 4] = v;
        }
        Ash[tr][c] = bf2f(u[(size_t)(row0 + tr) * 1024 + k0 + c]);
        __syncthreads();
        #pragma unroll
        for (int k = 0; k < 64; ++k)
            acc = fmaf(Ash[tr][k], Bsh[k][c], acc);
    }
    Cc[(size_t)(row0 + tr) * 64 + c] = acc;
}

// -------- dt_proj f32 GEMM (K=32) + softplus -> delta bf16 ------------------
#define BM 64
#define BN 64
#define BKK 16
__global__ __launch_bounds__(256) void gemm_dt(const float* __restrict__ A,
                                               const float* __restrict__ Bm,
                                               const float* __restrict__ bias,
                                               unsigned short* __restrict__ Cb,
                                               int lda, int ldb, int ldc) {
    __shared__ float As[BM][BKK + 4];
    __shared__ float Bs[BKK][BN];
    int tid = threadIdx.x;
    int n0 = blockIdx.x * BN;
    int m0 = blockIdx.y * BM;
    int tx4 = (tid & 15) << 2;
    int ty4 = (tid >> 4) << 2;
    int arow = tid >> 2, akk = (tid & 3) << 2;
    int brow = tid >> 4, bcol = (tid & 15) << 2;
    float acc[4][4] = {};
    for (int k0 = 0; k0 < 32; k0 += BKK) {
        float4 av = *(const float4*)&A[(size_t)(m0 + arow) * lda + k0 + akk];
        float4 bv = *(const float4*)&Bm[(size_t)(k0 + brow) * ldb + n0 + bcol];
        *(float4*)&As[arow][akk] = av;
        *(float4*)&Bs[brow][bcol] = bv;
        __syncthreads();
        #pragma unroll
        for (int k = 0; k < BKK; ++k) {
            float a0 = As[ty4 + 0][k];
            float a1 = As[ty4 + 1][k];
            float a2 = As[ty4 + 2][k];
            float a3 = As[ty4 + 3][k];
            float4 b = *(float4*)&Bs[k][tx4];
            acc[0][0] = fmaf(a0, b.x, acc[0][0]); acc[0][1] = fmaf(a0, b.y, acc[0][1]);
            acc[0][2] = fmaf(a0, b.z, acc[0][2]); acc[0][3] = fmaf(a0, b.w, acc[0][3]);
            acc[1][0] = fmaf(a1, b.x, acc[1][0]); acc[1][1] = fmaf(a1, b.y, acc[1][1]);
            acc[1][2] = fmaf(a1, b.z, acc[1][2]); acc[1][3] = fmaf(a1, b.w, acc[1][3]);
            acc[2][0] = fmaf(a2, b.x, acc[2][0]); acc[2][1] = fmaf(a2, b.y, acc[2][1]);
            acc[2][2] = fmaf(a2, b.z, acc[2][2]); acc[2][3] = fmaf(a2, b.w, acc[2][3]);
            acc[3][0] = fmaf(a3, b.x, acc[3][0]); acc[3][1] = fmaf(a3, b.y, acc[3][1]);
            acc[3][2] = fmaf(a3, b.z, acc[3][2]); acc[3][3] = fmaf(a3, b.w, acc[3][3]);
        }
        __syncthreads();
    }
    #pragma unroll
    for (int i = 0; i < 4; ++i) {
        int m = m0 + ty4 + i;
        float4 bb = *(const float4*)&bias[n0 + tx4];
        uint2 pv;
        pv.x = pack_bf2(softplus_f(acc[i][0] + bb.x), softplus_f(acc[i][1] + bb.y));
        pv.y = pack_bf2(softplus_f(acc[i][2] + bb.z), softplus_f(acc[i][3] + bb.w));
        *(uint2*)&Cb[(size_t)m * ldc + n0 + tx4] = pv;
    }
}

// ============ chunk-parallel selective scan (NC=64, bf16 state) =============
__global__ __launch_bounds__(256) void scan_p1i(const unsigned short* __restrict__ u,
                                                const unsigned short* __restrict__ delta,
                                                const float* __restrict__ xdbl,
                                                const float* __restrict__ A_log,
                                                unsigned short* __restrict__ aprod,
                                                unsigned short* __restrict__ hloc) {
    int tid = threadIdx.x;
    int d = blockIdx.x * 256 + tid;
    int b = blockIdx.y, c = blockIdx.z;
    int l0 = c * LC;
    __shared__ float sBC[LC][32];
    for (int i = tid; i < LC * 32; i += 256) {
        int l = i >> 5, j = i & 31;
        sBC[l][j] = xdbl[(size_t)(b * SEQ_L + l0 + l) * 64 + 32 + j];
    }
    __syncthreads();
    float A_[D_STATE], h[D_STATE], ap[D_STATE];
    #pragma unroll
    for (int n = 0; n < D_STATE; ++n) {
        A_[n] = -__expf(A_log[(size_t)d * D_STATE + n]);
        h[n] = 0.f; ap[n] = 1.f;
    }
    const unsigned short* ucol = u + (size_t)(b * SEQ_L + l0) * D_INNER + d;
    const unsigned short* dcol = delta + (size_t)(b * SEQ_L + l0) * D_INNER + d;
    for (int l = 0; l < LC; ++l) {
        float dtv = bf2f(dcol[l * D_INNER]);
        float uu = bf2f(ucol[l * D_INNER]);
        float du = dtv * uu;
        #pragma unroll
        for (int n = 0; n < D_STATE; ++n) {
            float e = __expf(dtv * A_[n]);
            h[n] = fmaf(e, h[n], du * sBC[l][n]);
            ap[n] *= e;
        }
    }
    #pragma unroll
    for (int n = 0; n < D_STATE; ++n) {
        size_t o = (((size_t)b * NC + c) * D_STATE + n) * D_INNER + d;
        aprod[o] = f2bf(ap[n]);
        hloc[o] = f2bf(h[n]);
    }
}

__global__ __launch_bounds__(256) void scan_p2(const unsigned short* __restrict__ aprod,
                                               unsigned short* __restrict__ hloc) {
    int d = blockIdx.x * 256 + threadIdx.x;
    int n = blockIdx.y;
    int b = blockIdx.z;
    float h = 0.f;
    #pragma unroll 4
    for (int c = 0; c < NC; ++c) {
        size_t o = (((size_t)b * NC + c) * D_STATE + n) * D_INNER + d;
        float ap = bf2f(aprod[o]);
        float lc = bf2f(hloc[o]);
        hloc[o] = f2bf(h);
        h = fmaf(ap, h, lc);
    }
}

__global__ __launch_bounds__(256) void scan_p3i(const unsigned short* __restrict__ u,
                                                const unsigned short* __restrict__ delta,
                                                const float* __restrict__ xdbl,
                                                const float* __restrict__ A_log,
                                                const float* __restrict__ Dp,
                                                const unsigned short* __restrict__ hinit,
                                                const unsigned short* __restrict__ xi,
                                                unsigned short* __restrict__ y) {
    int tid = threadIdx.x;
    int d = blockIdx.x * 256 + tid;
    int b = blockIdx.y, c = blockIdx.z;
    int l0 = c * LC;
    __shared__ float sBC[LC][32];
    for (int i = tid; i < LC * 32; i += 256) {
        int l = i >> 5, j = i & 31;
        sBC[l][j] = xdbl[(size_t)(b * SEQ_L + l0 + l) * 64 + 32 + j];
    }
    __syncthreads();
    float A_[D_STATE], h[D_STATE];
    #pragma unroll
    for (int n = 0; n < D_STATE; ++n) {
        A_[n] = -__expf(A_log[(size_t)d * D_STATE + n]);
        size_t o = (((size_t)b * NC + c) * D_STATE + n) * D_INNER + d;
        h[n] = bf2f(hinit[o]);
    }
    float Dd = Dp[d];
    const unsigned short* ucol = u  + (size_t)(b * SEQ_L + l0) * D_INNER + d;
    const unsigned short* dcol = delta + (size_t)(b * SEQ_L + l0) * D_INNER + d;
    const unsigned short* rcol = xi + (size_t)(b * SEQ_L + l0) * 2048 + 1024 + d;
    for (int l = 0; l < LC; ++l) {
        float dtv = bf2f(dcol[l * D_INNER]);
        float uu = bf2f(ucol[l * D_INNER]);
        float du = dtv * uu;
        float yv = 0.f;
        #pragma unroll
        for (int n = 0; n < D_STATE; ++n) {
            float e = __expf(dtv * A_[n]);
            h[n] = fmaf(e, h[n], du * sBC[l][n]);
            yv = fmaf(h[n], sBC[l][16 + n], yv);
        }
        yv = fmaf(uu, Dd, yv);
        float res = bf2f(rcol[l * 2048]);
        y[(size_t)(b * SEQ_L + l0 + l) * D_INNER + d] = f2bf(yv * silu_f(res));
    }
}

// ============== fused final rmsnorm + mean-pool (chunked over L) ============
__global__ __launch_bounds__(256) void rms_pool1(const float* __restrict__ x,
                                                 float* __restrict__ partial) {
    int blk = blockIdx.x;
    int b = blk >> 5, c = blk & 31;
    int wave = threadIdx.x >> 6, lane = threadIdx.x & 63;
    int row0 = b * SEQ_L + c * 32 + wave * 8;
    float4 a0 = make_float4(0.f, 0.f, 0.f, 0.f);
    float4 a1 = make_float4(0.f, 0.f, 0.f, 0.f);
    for (int r = 0; r < 8; ++r) {
        const float* xp = x + (size_t)(row0 + r) * D_MODEL;
        float4 v0 = *(const float4*)&xp[lane * 4];
        float4 v1 = *(const float4*)&xp[256 + lane * 4];
        float ss = v0.x*v0.x + v0.y*v0.y + v0.z*v0.z + v0.w*v0.w
                 + v1.x*v1.x + v1.y*v1.y + v1.z*v1.z + v1.w*v1.w;
        #pragma unroll
        for (int off = 32; off > 0; off >>= 1) ss += __shfl_xor(ss, off);
        float s = rsqrtf(ss * (1.f / D_MODEL) + 1e-5f);
        a0.x = fmaf(v0.x, s, a0.x); a0.y = fmaf(v0.y, s, a0.y);
        a0.z = fmaf(v0.z, s, a0.z); a0.w = fmaf(v0.w, s, a0.w);
        a1.x = fmaf(v1.x, s, a1.x); a1.y = fmaf(v1.y, s, a1.y);
        a1.z = fmaf(v1.z, s, a1.z); a1.w = fmaf(v1.w, s, a1.w);
    }
    __shared__ float red[4][512];
    *(float4*)&red[wave][lane * 4] = a0;
    *(float4*)&red[wave][256 + lane * 4] = a1;
    __syncthreads();
    int d = threadIdx.x * 2;
    float s0 = red[0][d] + red[1][d] + red[2][d] + red[3][d];
    float s1 = red[0][d+1] + red[1][d+1] + red[2][d+1] + red[3][d+1];
    partial[(size_t)blk * 512 + d]     = s0;
    partial[(size_t)blk * 512 + d + 1] = s1;
}

// ---- emb_proj k-split: 16 blocks read proj_w in parallel -------------------
__global__ __launch_bounds__(256) void embp1f(const float* __restrict__ ppart,
                                              const float* __restrict__ w,
                                              const float* __restrict__ pw,
                                              float* __restrict__ partial) {
    int b = blockIdx.x, kc = blockIdx.y;
    int t = threadIdx.x;
    __shared__ float sp[64];
    if (t < 64) {
        int dd = kc * 64 + t;
        float s = 0.f;
        #pragma unroll
        for (int c = 0; c < 32; ++c)
            s += ppart[((size_t)b * 32 + c) * 512 + dd];
        sp[t] = s * (1.f / SEQ_L) * w[dd];
    }
    __syncthreads();
    float acc = 0.f;
    #pragma unroll 8
    for (int i = 0; i < 64; ++i) {
        int k = kc * 64 + i;
        acc = fmaf(sp[i], pw[(size_t)k * 256 + t], acc);
    }
    partial[((size_t)b * 8 + kc) * 256 + t] = acc;
}

// ---- head: partial-reduce + bias -> emotion_emb, then logits (1 block) -----
__global__ __launch_bounds__(512) void head_kernel(const float* __restrict__ eparts,
                                                   const float* __restrict__ pb,
                                                   const float* __restrict__ cw,
                                                   const float* __restrict__ cb,
                                                   float* __restrict__ out) {
    __shared__ float se[2][256];
    int t = threadIdx.x;
    int b = t >> 8, e = t & 255;
    float s = pb[e];
    #pragma unroll
    for (int kc = 0; kc < 8; ++kc)
        s += eparts[((size_t)b * 8 + kc) * 256 + e];
    out[14 + b * 256 + e] = s;
    se[b][e] = s;
    __syncthreads();
    int wave = t >> 6, lane = t & 63;
    for (int idx = wave; idx < 14; idx += 8) {
        int bb = idx / 7, cc = idx % 7;
        float a = 0.f;
        #pragma unroll
        for (int i = 0; i < 4; ++i) {
            int k = lane + i * 64;
            a = fmaf(se[bb][k], cw[k * 7 + cc], a);
        }
        #pragma unroll
        for (int off = 32; off > 0; off >>= 1) a += __shfl_xor(a, off);
        if (lane == 0) out[bb * 7 + cc] = a + cb[cc];
    }
}

extern "C" void kernel_launch(void* const* d_in, const int* in_sizes, int n_in,
                              void* d_out, int out_size, void* d_ws, size_t ws_size,
                              hipStream_t stream) {
    const int*   ids    = (const int*)d_in[0];
    const float* emb    = (const float*)d_in[1];
    const float* norm_w = (const float*)d_in[2];
    const float* in_w   = (const float*)d_in[3];
    const float* conv_w = (const float*)d_in[4];
    const float* conv_b = (const float*)d_in[5];
    const float* xp_w   = (const float*)d_in[6];
    const float* dt_w   = (const float*)d_in[7];
    const float* dt_b   = (const float*)d_in[8];
    const float* A_log  = (const float*)d_in[9];
    const float* Dp     = (const float*)d_in[10];
    const float* out_w  = (const float*)d_in[11];
    const float* normf  = (const float*)d_in[12];
    const float* proj_w = (const float*)d_in[13];
    const float* proj_b = (const float*)d_in[14];
    const float* cls_w  = (const float*)d_in[15];
    const float* cls_b  = (const float*)d_in[16];
    float* out = (float*)d_out;

    float* p = (float*)d_ws;
    float* x      = p; p += 1 << 20;          // [2048][512] f32
    float* xnr    = p; p += 1 << 20;          // xn_bf / ppart
    float* xrr    = p; p += 2 << 20;          // xr_bf [2048][2048] bf16
    float* urr    = p; p += 1 << 20;          // u_bf  [2048][1024] bf16
    float* deltab = p; p += 1 << 20;          // delta [2048][1024] bf16
    float* xdbl   = p; p += 1 << 17;          // [2048][64] f32
    float* wreg   = p; p += 1572864;          // in_wt x2 + out_wt x2 (bf16)
    float* aprodr = p; p += 1 << 20;          // aprod bf16 [2][64][16][1024]
    float* hlocr  = p; p += 1 << 20;          // hloc  bf16 same shape
    float* ybr    = p; p += 1 << 20;          // yb_bf [2048][1024] bf16
    float* eparts = p; p += 4096;             // [2][8][256] f32

    unsigned short* xn_bf  = (unsigned short*)xnr;
    float*          ppart  = xnr;
    unsigned short* xr_bf  = (unsigned short*)xrr;
    unsigned short* u_bf   = (unsigned short*)urr;
    unsigned short* dt_bf  = (unsigned short*)deltab;
    unsigned short* in_wt_all  = (unsigned short*)wreg;
    unsigned short* out_wt_all = (unsigned short*)(wreg + (1 << 20));
    unsigned short* aprod  = (unsigned short*)aprodr;
    unsigned short* hloc   = (unsigned short*)hlocr;
    unsigned short* yb_bf  = (unsigned short*)ybr;

    init_kernel<<<3584, 256, 0, stream>>>(
        ids, emb, norm_w, in_w, out_w, x, xn_bf, in_wt_all, out_wt_all);

    for (int i = 0; i < NLAYER; ++i) {
        unsigned short* in_wt  = in_wt_all  + (size_t)i * 2048 * 512;
        unsigned short* out_wt = out_wt_all + (size_t)i * 512 * 1024;
        const float* cwi  = conv_w + (size_t)i * D_INNER * 4;
        const float* cbi  = conv_b + (size_t)i * D_INNER;
        const float* dtwi = dt_w + (size_t)i * DT_RANK * D_INNER;
        const float* dtbi = dt_b + (size_t)i * D_INNER;
        const float* Ali  = A_log + (size_t)i * D_INNER * D_STATE;
        const float* Dpi  = Dp + (size_t)i * D_INNER;

        if (i > 0)
            rmsnorm_bf_kernel<<<M_ROWS, 64, 0, stream>>>(x, norm_w + i * D_MODEL, xn_bf);
        gemm_mfma_t<128, 64, 3><<<dim3(2048 / 64, M_ROWS / 128), 256, 0, stream>>>(
            xn_bf, in_wt, nullptr, xr_bf, 512, 2048);
        conv_bf_kernel<<<(M_ROWS * D_INNER) / 256, 256, 0, stream>>>(
            xr_bf, cwi, cbi, u_bf);
        xproj_kernel<<<M_ROWS / 4, 256, 0, stream>>>(
            u_bf, xp_w + (size_t)i * D_INNER * 64, xdbl);
        gemm_dt<<<dim3(1024 / BN, M_ROWS / BM), 256, 0, stream>>>(
            xdbl, dtwi, dtbi, dt_bf, 64, 1024, 1024);
        scan_p1i<<<dim3(4, BATCH, NC), 256, 0, stream>>>(
            u_bf, dt_bf, xdbl, Ali, aprod, hloc);
        scan_p2<<<dim3(4, D_STATE, BATCH), 256, 0, stream>>>(aprod, hloc);
        scan_p3i<<<dim3(4, BATCH, NC), 256, 0, stream>>>(
            u_bf, dt_bf, xdbl, Ali, Dpi, hloc, xr_bf, yb_bf);
        gemm_mfma_t<64, 32, 2><<<dim3(512 / 32, M_ROWS / 64), 256, 0, stream>>>(
            yb_bf, out_wt, x, nullptr, 1024, 512);
    }

    rms_pool1<<<BATCH * 32, 256, 0, stream>>>(x, ppart);
    embp1f<<<dim3(BATCH, 8), 256, 0, stream>>>(ppart, normf, proj_w, eparts);
    head_kernel<<<1, 512, 0, stream>>>(eparts, proj_b, cls_w, cls_b, out);
}